// Round 1
// baseline (284.703 us; speedup 1.0000x reference)
//
#include <hip/hip_runtime.h>

#define D_MODEL 1024
#define NH 16
#define DK 64
#define BB 2
#define SS 2048
#define M_TOT (BB*SS)

typedef float f32x4 __attribute__((ext_vector_type(4)));
typedef __bf16 bf16x8 __attribute__((ext_vector_type(8)));

__device__ __forceinline__ unsigned short f2bf(float f){
  unsigned int u = __float_as_uint(f);
  unsigned int r = (u + 0x7fffu + ((u >> 16) & 1u)) >> 16;
  return (unsigned short)r;
}

__device__ __forceinline__ void gload_lds16(const void* g, void* l){
  __builtin_amdgcn_global_load_lds((const __attribute__((address_space(1))) void*)g,
                                   (__attribute__((address_space(3))) void*)l,
                                   16, 0, 0);
}

// ---------------- fp32 -> bf16 elementwise convert (vectorized) ----------------
__global__ __launch_bounds__(256) void cvt_bf16_kernel(const float* __restrict__ in,
                                                       unsigned short* __restrict__ out,
                                                       int n4){
  int i = blockIdx.x * 256 + threadIdx.x;
  if (i < n4){
    float4 f = ((const float4*)in)[i];
    ushort4 o;
    o.x = f2bf(f.x); o.y = f2bf(f.y); o.z = f2bf(f.z); o.w = f2bf(f.w);
    ((ushort4*)out)[i] = o;
  }
}

// ---------------- fp32 [K][N] -> bf16 [N][K] transpose-convert ----------------
__global__ __launch_bounds__(256) void transpose_cvt(const float* __restrict__ w,
                                                     unsigned short* __restrict__ wt,
                                                     int N){
  __shared__ float tile[64][65];
  const int bx = blockIdx.x * 64;  // col base of w (= row base of wt)
  const int by = blockIdx.y * 64;  // row base of w
  const int t = threadIdx.x;
  #pragma unroll
  for (int i = 0; i < 16; ++i){
    int idx = t + i * 256;
    int r = idx >> 6, c = idx & 63;
    tile[r][c] = w[(size_t)(by + r) * N + bx + c];
  }
  __syncthreads();
  #pragma unroll
  for (int i = 0; i < 16; ++i){
    int idx = t + i * 256;
    int r = idx >> 6, c = idx & 63;
    wt[(size_t)(bx + r) * N + by + c] = f2bf(tile[c][r]);
  }
}

// ---------------- bf16 GEMM: C[M,N] = A[M,K] * Bt[N,K]^T ----------------
// MODE 0: bf16 output, head-major scatter [(b*NH+h)*SS+s]*DK+dk  (projections)
// MODE 1: fp32 output, plain row-major [m*N+n]                    (w_o)
template<int MODE>
__global__ __launch_bounds__(256) void gemm_bt(const unsigned short* __restrict__ A,
                                               const unsigned short* __restrict__ Bt,
                                               void* __restrict__ Cout,
                                               int M, int N, int K){
  __shared__ unsigned short Al[2][128 * 32];
  __shared__ unsigned short Bl[2][128 * 32];
  const int tid = threadIdx.x;
  const int wid = tid >> 6, lane = tid & 63;
  const int lr = lane & 15, lg = lane >> 4;
  const int wm = wid >> 1, wn = wid & 1;
  const int bm = blockIdx.x, bn = blockIdx.y;

  f32x4 acc[4][4];
  #pragma unroll
  for (int i = 0; i < 4; ++i)
    #pragma unroll
    for (int j = 0; j < 4; ++j)
      acc[i][j] = (f32x4){0.f, 0.f, 0.f, 0.f};

  const int nkt = K >> 5;

  auto stage = [&](int buf, int kt){
    #pragma unroll
    for (int r = 0; r < 2; ++r){
      int vt = tid + r * 256;
      int row = vt >> 2, c8 = (vt & 3) * 8;
      const unsigned short* ga = A  + (size_t)(bm * 128 + row) * K + kt * 32 + c8;
      const unsigned short* gb = Bt + (size_t)(bn * 128 + row) * K + kt * 32 + c8;
      // wave-uniform LDS base; HW scatters lane*16B
      unsigned short* la = &Al[buf][((tid >> 6) << 9) + r * 2048];
      unsigned short* lb = &Bl[buf][((tid >> 6) << 9) + r * 2048];
      gload_lds16(ga, la);
      gload_lds16(gb, lb);
    }
  };

  stage(0, 0);
  int cur = 0;
  for (int kt = 0; kt < nkt; ++kt){
    __syncthreads();                       // drains vmcnt for stage(cur)
    if (kt + 1 < nkt) stage(cur ^ 1, kt + 1);
    bf16x8 af[4], bfr[4];
    #pragma unroll
    for (int i = 0; i < 4; ++i)
      af[i] = *(const bf16x8*)&Al[cur][(wm * 64 + i * 16 + lr) * 32 + lg * 8];
    #pragma unroll
    for (int j = 0; j < 4; ++j)
      bfr[j] = *(const bf16x8*)&Bl[cur][(wn * 64 + j * 16 + lr) * 32 + lg * 8];
    #pragma unroll
    for (int i = 0; i < 4; ++i)
      #pragma unroll
      for (int j = 0; j < 4; ++j)
        acc[i][j] = __builtin_amdgcn_mfma_f32_16x16x32_bf16(af[i], bfr[j], acc[i][j], 0, 0, 0);
    cur ^= 1;
  }

  if (MODE == 0){
    unsigned short* O = (unsigned short*)Cout;
    #pragma unroll
    for (int i = 0; i < 4; ++i){
      int row0 = bm * 128 + wm * 64 + i * 16 + lg * 4;
      #pragma unroll
      for (int j = 0; j < 4; ++j){
        int col = bn * 128 + wn * 64 + j * 16 + lr;
        int h = col >> 6, dk = col & 63;
        #pragma unroll
        for (int p = 0; p < 4; ++p){
          int rowm = row0 + p;
          int b = rowm >> 11, s = rowm & 2047;
          O[((size_t)(b * NH + h) * SS + s) * DK + dk] = f2bf(acc[i][j][p]);
        }
      }
    }
  } else {
    float* O = (float*)Cout;
    #pragma unroll
    for (int i = 0; i < 4; ++i){
      int row0 = bm * 128 + wm * 64 + i * 16 + lg * 4;
      #pragma unroll
      for (int j = 0; j < 4; ++j){
        int col = bn * 128 + wn * 64 + j * 16 + lr;
        #pragma unroll
        for (int p = 0; p < 4; ++p)
          O[(size_t)(row0 + p) * N + col] = acc[i][j][p];
      }
    }
  }
}

// ---------------- causal flash attention ----------------
// Qh/Kh/Vh: [B*NH][SS][DK] bf16.  Oc: [B][SS][D_MODEL] bf16 (heads concat).
__global__ __launch_bounds__(256) void attn_kernel(const unsigned short* __restrict__ Qh,
                                                   const unsigned short* __restrict__ Kh,
                                                   const unsigned short* __restrict__ Vh,
                                                   unsigned short* __restrict__ Oc){
  __shared__ unsigned short Vt[64][80];      // V^T tile [d][key], padded
  __shared__ unsigned short Pl[4][16][80];   // per-wave P [q][key], padded
  const int qt = blockIdx.x, bh = blockIdx.y;
  const int tid = threadIdx.x, wid = tid >> 6, lane = tid & 63;
  const int lr = lane & 15, lg = lane >> 4;
  const int q0 = qt * 64 + wid * 16;

  const unsigned short* qp = Qh + ((size_t)bh * SS + q0 + lr) * DK + lg * 8;
  bf16x8 aq0 = *(const bf16x8*)qp;
  bf16x8 aq1 = *(const bf16x8*)(qp + 32);

  f32x4 o[4];
  #pragma unroll
  for (int df = 0; df < 4; ++df) o[df] = (f32x4){0.f, 0.f, 0.f, 0.f};
  float m[4], lsum[4];
  #pragma unroll
  for (int p = 0; p < 4; ++p){ m[p] = -1e30f; lsum[p] = 0.f; }

  for (int kt = 0; kt <= qt; ++kt){
    const int k0 = kt * 64;
    // stage V^T tile (cooperative)
    #pragma unroll
    for (int jj = 0; jj < 2; ++jj){
      int c = tid + jj * 256;
      int key = c >> 3, d0 = (c & 7) * 8;
      uint4 vv = *(const uint4*)&Vh[((size_t)bh * SS + k0 + key) * DK + d0];
      const unsigned short* vs = (const unsigned short*)&vv;
      #pragma unroll
      for (int e = 0; e < 8; ++e) Vt[d0 + e][key] = vs[e];
    }
    // scores: 16 q-rows x 64 keys
    f32x4 sc[4];
    #pragma unroll
    for (int cf = 0; cf < 4; ++cf){
      const unsigned short* kp = Kh + ((size_t)bh * SS + k0 + cf * 16 + lr) * DK + lg * 8;
      bf16x8 bk0 = *(const bf16x8*)kp;
      bf16x8 bk1 = *(const bf16x8*)(kp + 32);
      f32x4 s = (f32x4){0.f, 0.f, 0.f, 0.f};
      s = __builtin_amdgcn_mfma_f32_16x16x32_bf16(aq0, bk0, s, 0, 0, 0);
      s = __builtin_amdgcn_mfma_f32_16x16x32_bf16(aq1, bk1, s, 0, 0, 0);
      sc[cf] = s;
    }
    // scale + causal mask
    #pragma unroll
    for (int cf = 0; cf < 4; ++cf){
      int kk = k0 + cf * 16 + lr;
      #pragma unroll
      for (int p = 0; p < 4; ++p){
        float vsc = sc[cf][p] * 0.125f;
        int qq = q0 + lg * 4 + p;
        sc[cf][p] = (kk > qq) ? -1e9f : vsc;
      }
    }
    // online softmax (reduce across the 16 col-lanes)
    float fac[4], rs[4];
    #pragma unroll
    for (int p = 0; p < 4; ++p){
      float t = fmaxf(fmaxf(sc[0][p], sc[1][p]), fmaxf(sc[2][p], sc[3][p]));
      #pragma unroll
      for (int d = 1; d < 16; d <<= 1) t = fmaxf(t, __shfl_xor(t, d));
      float mn = fmaxf(m[p], t);
      fac[p] = __expf(m[p] - mn);
      m[p] = mn;
      rs[p] = 0.f;
    }
    #pragma unroll
    for (int cf = 0; cf < 4; ++cf)
      #pragma unroll
      for (int p = 0; p < 4; ++p){
        float e = __expf(sc[cf][p] - m[p]);
        sc[cf][p] = e;
        rs[p] += e;
      }
    #pragma unroll
    for (int p = 0; p < 4; ++p){
      float r = rs[p];
      #pragma unroll
      for (int d = 1; d < 16; d <<= 1) r += __shfl_xor(r, d);
      lsum[p] = lsum[p] * fac[p] + r;
    }
    // P -> LDS (bf16), rescale O
    #pragma unroll
    for (int cf = 0; cf < 4; ++cf)
      #pragma unroll
      for (int p = 0; p < 4; ++p)
        Pl[wid][lg * 4 + p][cf * 16 + lr] = f2bf(sc[cf][p]);
    #pragma unroll
    for (int df = 0; df < 4; ++df)
      #pragma unroll
      for (int p = 0; p < 4; ++p)
        o[df][p] *= fac[p];
    __syncthreads();   // Vt staged + P written
    // PV
    bf16x8 pa0 = *(const bf16x8*)&Pl[wid][lr][lg * 8];
    bf16x8 pa1 = *(const bf16x8*)&Pl[wid][lr][32 + lg * 8];
    #pragma unroll
    for (int df = 0; df < 4; ++df){
      bf16x8 vb0 = *(const bf16x8*)&Vt[df * 16 + lr][lg * 8];
      bf16x8 vb1 = *(const bf16x8*)&Vt[df * 16 + lr][32 + lg * 8];
      o[df] = __builtin_amdgcn_mfma_f32_16x16x32_bf16(pa0, vb0, o[df], 0, 0, 0);
      o[df] = __builtin_amdgcn_mfma_f32_16x16x32_bf16(pa1, vb1, o[df], 0, 0, 0);
    }
    __syncthreads();   // before Vt/Pl overwrite
  }
  // epilogue: O / lsum -> concat layout
  const int b = bh >> 4, h = bh & 15;
  #pragma unroll
  for (int p = 0; p < 4; ++p){
    float inv = 1.0f / lsum[p];
    size_t rowbase = ((size_t)b * SS + q0 + lg * 4 + p) * D_MODEL + h * DK;
    #pragma unroll
    for (int df = 0; df < 4; ++df)
      Oc[rowbase + df * 16 + lr] = f2bf(o[df][p] * inv);
  }
}

extern "C" void kernel_launch(void* const* d_in, const int* in_sizes, int n_in,
                              void* d_out, int out_size, void* d_ws, size_t ws_size,
                              hipStream_t stream){
  const float* q  = (const float*)d_in[0];
  const float* k  = (const float*)d_in[1];
  const float* v  = (const float*)d_in[2];
  // d_in[3]: causal mask (deterministic tril) — hardcoded in attn kernel
  const float* wq = (const float*)d_in[4];
  const float* wk = (const float*)d_in[5];
  const float* wv = (const float*)d_in[6];
  const float* wo = (const float*)d_in[7];
  float* out = (float*)d_out;

  char* ws = (char*)d_ws;
  const size_t MB = 1024 * 1024;
  unsigned short* qb    = (unsigned short*)(ws + 0 * MB);
  unsigned short* kb    = (unsigned short*)(ws + 8 * MB);
  unsigned short* vb    = (unsigned short*)(ws + 16 * MB);
  unsigned short* wqT   = (unsigned short*)(ws + 24 * MB);
  unsigned short* wkT   = (unsigned short*)(ws + 26 * MB);
  unsigned short* wvT   = (unsigned short*)(ws + 28 * MB);
  unsigned short* woT   = (unsigned short*)(ws + 30 * MB);
  unsigned short* Qh    = (unsigned short*)(ws + 32 * MB);
  unsigned short* Kh    = (unsigned short*)(ws + 40 * MB);
  unsigned short* Vh    = (unsigned short*)(ws + 48 * MB);
  unsigned short* attnb = (unsigned short*)(ws + 56 * MB);

  const int n4 = (M_TOT * D_MODEL) / 4;  // 1048576
  cvt_bf16_kernel<<<n4 / 256, 256, 0, stream>>>(q, qb, n4);
  cvt_bf16_kernel<<<n4 / 256, 256, 0, stream>>>(k, kb, n4);
  cvt_bf16_kernel<<<n4 / 256, 256, 0, stream>>>(v, vb, n4);

  dim3 tg(16, 16);
  transpose_cvt<<<tg, 256, 0, stream>>>(wq, wqT, D_MODEL);
  transpose_cvt<<<tg, 256, 0, stream>>>(wk, wkT, D_MODEL);
  transpose_cvt<<<tg, 256, 0, stream>>>(wv, wvT, D_MODEL);
  transpose_cvt<<<tg, 256, 0, stream>>>(wo, woT, D_MODEL);

  dim3 gg(M_TOT / 128, D_MODEL / 128);   // (32, 8)
  gemm_bt<0><<<gg, 256, 0, stream>>>(qb, wqT, (void*)Qh, M_TOT, D_MODEL, D_MODEL);
  gemm_bt<0><<<gg, 256, 0, stream>>>(kb, wkT, (void*)Kh, M_TOT, D_MODEL, D_MODEL);
  gemm_bt<0><<<gg, 256, 0, stream>>>(vb, wvT, (void*)Vh, M_TOT, D_MODEL, D_MODEL);

  dim3 ga(SS / 64, BB * NH);             // (32, 32)
  attn_kernel<<<ga, 256, 0, stream>>>(Qh, Kh, Vh, attnb);

  gemm_bt<1><<<gg, 256, 0, stream>>>(attnb, woT, (void*)out, M_TOT, D_MODEL, D_MODEL);
}

// Round 2
// 241.669 us; speedup vs baseline: 1.1781x; 1.1781x over previous
//
#include <hip/hip_runtime.h>

#define D_MODEL 1024
#define NH 16
#define DK 64
#define BB 2
#define SS 2048
#define M_TOT (BB*SS)

typedef float f32x4 __attribute__((ext_vector_type(4)));
typedef __bf16 bf16x8 __attribute__((ext_vector_type(8)));

__device__ __forceinline__ unsigned short f2bf(float f){
  unsigned int u = __float_as_uint(f);
  unsigned int r = (u + 0x7fffu + ((u >> 16) & 1u)) >> 16;
  return (unsigned short)r;
}

__device__ __forceinline__ void gload_lds16(const void* g, void* l){
  __builtin_amdgcn_global_load_lds((const __attribute__((address_space(1))) void*)g,
                                   (__attribute__((address_space(3))) void*)l,
                                   16, 0, 0);
}

// ---------------- fp32 -> bf16 elementwise convert (vectorized) ----------------
__global__ __launch_bounds__(256) void cvt_bf16_kernel(const float* __restrict__ in,
                                                       unsigned short* __restrict__ out,
                                                       int n4){
  int i = blockIdx.x * 256 + threadIdx.x;
  if (i < n4){
    float4 f = ((const float4*)in)[i];
    ushort4 o;
    o.x = f2bf(f.x); o.y = f2bf(f.y); o.z = f2bf(f.z); o.w = f2bf(f.w);
    ((ushort4*)out)[i] = o;
  }
}

// ---------------- fp32 [K][N] -> bf16 [N][K] transpose-convert ----------------
__global__ __launch_bounds__(256) void transpose_cvt(const float* __restrict__ w,
                                                     unsigned short* __restrict__ wt,
                                                     int N){
  __shared__ float tile[64][65];
  const int bx = blockIdx.x * 64;
  const int by = blockIdx.y * 64;
  const int t = threadIdx.x;
  #pragma unroll
  for (int i = 0; i < 16; ++i){
    int idx = t + i * 256;
    int r = idx >> 6, c = idx & 63;
    tile[r][c] = w[(size_t)(by + r) * N + bx + c];
  }
  __syncthreads();
  #pragma unroll
  for (int i = 0; i < 16; ++i){
    int idx = t + i * 256;
    int r = idx >> 6, c = idx & 63;
    wt[(size_t)(bx + r) * N + by + c] = f2bf(tile[c][r]);
  }
}

// ---------------- bf16 GEMM: C[M,N] = A[M,K] * Bt[N,K]^T ----------------
// MODE 0: bf16 out, head-major scatter [(b*NH+h)*SS+s]*DK+dk   (Q,K proj)
// MODE 1: fp32 out, plain row-major [m*N+n]                    (w_o)
// MODE 2: bf16 out, head-major TRANSPOSED [(b*NH+h)*DK+dk]*SS+s (V proj)
template<int MODE>
__global__ __launch_bounds__(256) void gemm_bt(const unsigned short* __restrict__ A,
                                               const unsigned short* __restrict__ Bt,
                                               void* __restrict__ Cout,
                                               int M, int N, int K){
  __shared__ unsigned short Al[2][128 * 32];
  __shared__ unsigned short Bl[2][128 * 32];
  const int tid = threadIdx.x;
  const int wid = tid >> 6, lane = tid & 63;
  const int lr = lane & 15, lg = lane >> 4;
  const int wm = wid >> 1, wn = wid & 1;
  const int bm = blockIdx.x, bn = blockIdx.y;

  f32x4 acc[4][4];
  #pragma unroll
  for (int i = 0; i < 4; ++i)
    #pragma unroll
    for (int j = 0; j < 4; ++j)
      acc[i][j] = (f32x4){0.f, 0.f, 0.f, 0.f};

  const int nkt = K >> 5;

  auto stage = [&](int buf, int kt){
    #pragma unroll
    for (int r = 0; r < 2; ++r){
      int vt = tid + r * 256;
      int row = vt >> 2, c8 = (vt & 3) * 8;
      const unsigned short* ga = A  + (size_t)(bm * 128 + row) * K + kt * 32 + c8;
      const unsigned short* gb = Bt + (size_t)(bn * 128 + row) * K + kt * 32 + c8;
      unsigned short* la = &Al[buf][((tid >> 6) << 9) + r * 2048];
      unsigned short* lb = &Bl[buf][((tid >> 6) << 9) + r * 2048];
      gload_lds16(ga, la);
      gload_lds16(gb, lb);
    }
  };

  stage(0, 0);
  int cur = 0;
  for (int kt = 0; kt < nkt; ++kt){
    __syncthreads();
    if (kt + 1 < nkt) stage(cur ^ 1, kt + 1);
    bf16x8 af[4], bfr[4];
    #pragma unroll
    for (int i = 0; i < 4; ++i)
      af[i] = *(const bf16x8*)&Al[cur][(wm * 64 + i * 16 + lr) * 32 + lg * 8];
    #pragma unroll
    for (int j = 0; j < 4; ++j)
      bfr[j] = *(const bf16x8*)&Bl[cur][(wn * 64 + j * 16 + lr) * 32 + lg * 8];
    #pragma unroll
    for (int i = 0; i < 4; ++i)
      #pragma unroll
      for (int j = 0; j < 4; ++j)
        acc[i][j] = __builtin_amdgcn_mfma_f32_16x16x32_bf16(af[i], bfr[j], acc[i][j], 0, 0, 0);
    cur ^= 1;
  }

  if (MODE == 0){
    unsigned short* O = (unsigned short*)Cout;
    #pragma unroll
    for (int i = 0; i < 4; ++i){
      int row0 = bm * 128 + wm * 64 + i * 16 + lg * 4;
      #pragma unroll
      for (int j = 0; j < 4; ++j){
        int col = bn * 128 + wn * 64 + j * 16 + lr;
        int h = col >> 6, dk = col & 63;
        #pragma unroll
        for (int p = 0; p < 4; ++p){
          int rowm = row0 + p;
          int b = rowm >> 11, s = rowm & 2047;
          O[((size_t)(b * NH + h) * SS + s) * DK + dk] = f2bf(acc[i][j][p]);
        }
      }
    }
  } else if (MODE == 2){
    unsigned short* O = (unsigned short*)Cout;
    #pragma unroll
    for (int i = 0; i < 4; ++i){
      int row0 = bm * 128 + wm * 64 + i * 16 + lg * 4;
      int b = row0 >> 11, s = row0 & 2047;
      #pragma unroll
      for (int j = 0; j < 4; ++j){
        int col = bn * 128 + wn * 64 + j * 16 + lr;
        int h = col >> 6, dk = col & 63;
        ushort4 o4;
        o4.x = f2bf(acc[i][j][0]); o4.y = f2bf(acc[i][j][1]);
        o4.z = f2bf(acc[i][j][2]); o4.w = f2bf(acc[i][j][3]);
        *(ushort4*)&O[((size_t)(b * NH + h) * DK + dk) * SS + s] = o4;
      }
    }
  } else {
    float* O = (float*)Cout;
    #pragma unroll
    for (int i = 0; i < 4; ++i){
      int row0 = bm * 128 + wm * 64 + i * 16 + lg * 4;
      #pragma unroll
      for (int j = 0; j < 4; ++j){
        int col = bn * 128 + wn * 64 + j * 16 + lr;
        #pragma unroll
        for (int p = 0; p < 4; ++p)
          O[(size_t)(row0 + p) * N + col] = acc[i][j][p];
      }
    }
  }
}

// ---------------- causal flash attention, barrier-free ----------------
// Qh/Kh: [B*NH][SS][DK] bf16.  VhT: [B*NH][DK][SS] bf16.
// Oc: [B][SS][D_MODEL] bf16 (heads concat).
// Block = 4 waves, 64 q-rows (16/wave). Block px handles q-tiles {px, 31-px}
// (33 K-tile steps each -> perfect causal load balance). No __syncthreads:
// only LDS use is the per-wave-private P transpose.
__global__ __launch_bounds__(256) void attn_kernel(const unsigned short* __restrict__ Qh,
                                                   const unsigned short* __restrict__ Kh,
                                                   const unsigned short* __restrict__ VhT,
                                                   unsigned short* __restrict__ Oc){
  __shared__ unsigned short Pl[4][16][72];   // [wave][q][k], pitch 72 (144B, 16B-aligned rows)
  const int px = blockIdx.x, bh = blockIdx.y;
  const int tid = threadIdx.x, wid = tid >> 6, lane = tid & 63;
  const int lr = lane & 15, lg = lane >> 4;
  const int b = bh >> 4, h = bh & 15;
  const size_t kvbase = (size_t)bh * SS * DK;   // same extent for Kh and VhT

  #pragma unroll 1
  for (int half = 0; half < 2; ++half){
    const int qt = half ? (31 - px) : px;
    const int q0 = qt * 64 + wid * 16;

    const unsigned short* qp = Qh + kvbase + (size_t)(q0 + lr) * DK + lg * 8;
    bf16x8 aq0 = *(const bf16x8*)qp;
    bf16x8 aq1 = *(const bf16x8*)(qp + 32);

    f32x4 o[4];
    #pragma unroll
    for (int df = 0; df < 4; ++df) o[df] = (f32x4){0.f, 0.f, 0.f, 0.f};
    float m[4], ls[4];
    #pragma unroll
    for (int p = 0; p < 4; ++p){ m[p] = -1e30f; ls[p] = 0.f; }

    for (int kt = 0; kt <= qt; ++kt){
      const int k0 = kt * 64;
      // --- load K fragments (A-layout rows) and V^T fragments (B-layout rows) ---
      bf16x8 bk[4][2], vb[4][2];
      #pragma unroll
      for (int cf = 0; cf < 4; ++cf){
        const unsigned short* kp = Kh + kvbase + (size_t)(k0 + cf * 16 + lr) * DK + lg * 8;
        bk[cf][0] = *(const bf16x8*)kp;
        bk[cf][1] = *(const bf16x8*)(kp + 32);
      }
      #pragma unroll
      for (int df = 0; df < 4; ++df){
        const unsigned short* vp = VhT + kvbase + (size_t)(df * 16 + lr) * SS + k0 + lg * 8;
        vb[df][0] = *(const bf16x8*)vp;
        vb[df][1] = *(const bf16x8*)(vp + 32);
      }
      // --- scores ---
      f32x4 sc[4];
      #pragma unroll
      for (int cf = 0; cf < 4; ++cf){
        f32x4 s = (f32x4){0.f, 0.f, 0.f, 0.f};
        s = __builtin_amdgcn_mfma_f32_16x16x32_bf16(aq0, bk[cf][0], s, 0, 0, 0);
        s = __builtin_amdgcn_mfma_f32_16x16x32_bf16(aq1, bk[cf][1], s, 0, 0, 0);
        #pragma unroll
        for (int p = 0; p < 4; ++p) s[p] *= 0.125f;
        sc[cf] = s;
      }
      // causal mask: only the diagonal K-tile needs it (wave-uniform branch)
      if (kt == qt){
        #pragma unroll
        for (int cf = 0; cf < 4; ++cf){
          int kk = cf * 16 + lr;
          #pragma unroll
          for (int p = 0; p < 4; ++p){
            int qq = wid * 16 + lg * 4 + p;
            if (kk > qq) sc[cf][p] = -1e9f;
          }
        }
      }
      // --- online softmax (reduce over k = 16 lr-lanes x 4 frags) ---
      float fac[4];
      #pragma unroll
      for (int p = 0; p < 4; ++p){
        float t = fmaxf(fmaxf(sc[0][p], sc[1][p]), fmaxf(sc[2][p], sc[3][p]));
        #pragma unroll
        for (int d = 1; d < 16; d <<= 1) t = fmaxf(t, __shfl_xor(t, d));
        float mn = fmaxf(m[p], t);
        fac[p] = __expf(m[p] - mn);
        m[p] = mn;
      }
      float rs[4] = {0.f, 0.f, 0.f, 0.f};
      #pragma unroll
      for (int cf = 0; cf < 4; ++cf)
        #pragma unroll
        for (int p = 0; p < 4; ++p){
          float e = __expf(sc[cf][p] - m[p]);
          sc[cf][p] = e;
          rs[p] += e;
        }
      #pragma unroll
      for (int p = 0; p < 4; ++p){
        float r = rs[p];
        #pragma unroll
        for (int d = 1; d < 16; d <<= 1) r += __shfl_xor(r, d);
        ls[p] = ls[p] * fac[p] + r;
      }
      // --- P -> LDS (per-wave private), rescale O ---
      #pragma unroll
      for (int cf = 0; cf < 4; ++cf)
        #pragma unroll
        for (int p = 0; p < 4; ++p)
          Pl[wid][lg * 4 + p][cf * 16 + lr] = f2bf(sc[cf][p]);
      #pragma unroll
      for (int df = 0; df < 4; ++df)
        #pragma unroll
        for (int p = 0; p < 4; ++p)
          o[df][p] *= fac[p];
      // --- PV (same-wave LDS dependency; compiler inserts lgkmcnt) ---
      bf16x8 pa0 = *(const bf16x8*)&Pl[wid][lr][lg * 8];
      bf16x8 pa1 = *(const bf16x8*)&Pl[wid][lr][32 + lg * 8];
      #pragma unroll
      for (int df = 0; df < 4; ++df){
        o[df] = __builtin_amdgcn_mfma_f32_16x16x32_bf16(pa0, vb[df][0], o[df], 0, 0, 0);
        o[df] = __builtin_amdgcn_mfma_f32_16x16x32_bf16(pa1, vb[df][1], o[df], 0, 0, 0);
      }
    }
    // --- epilogue ---
    #pragma unroll
    for (int p = 0; p < 4; ++p){
      float inv = 1.0f / ls[p];
      size_t rowbase = ((size_t)b * SS + q0 + lg * 4 + p) * D_MODEL + h * DK;
      #pragma unroll
      for (int df = 0; df < 4; ++df)
        Oc[rowbase + df * 16 + lr] = f2bf(o[df][p] * inv);
    }
  }
}

extern "C" void kernel_launch(void* const* d_in, const int* in_sizes, int n_in,
                              void* d_out, int out_size, void* d_ws, size_t ws_size,
                              hipStream_t stream){
  const float* q  = (const float*)d_in[0];
  const float* k  = (const float*)d_in[1];
  const float* v  = (const float*)d_in[2];
  // d_in[3]: causal mask (deterministic tril) — hardcoded in attn kernel
  const float* wq = (const float*)d_in[4];
  const float* wk = (const float*)d_in[5];
  const float* wv = (const float*)d_in[6];
  const float* wo = (const float*)d_in[7];
  float* out = (float*)d_out;

  char* ws = (char*)d_ws;
  const size_t MB = 1024 * 1024;
  unsigned short* qb    = (unsigned short*)(ws + 0 * MB);
  unsigned short* kb    = (unsigned short*)(ws + 8 * MB);
  unsigned short* vb    = (unsigned short*)(ws + 16 * MB);
  unsigned short* wqT   = (unsigned short*)(ws + 24 * MB);
  unsigned short* wkT   = (unsigned short*)(ws + 26 * MB);
  unsigned short* wvT   = (unsigned short*)(ws + 28 * MB);
  unsigned short* woT   = (unsigned short*)(ws + 30 * MB);
  unsigned short* Qh    = (unsigned short*)(ws + 32 * MB);
  unsigned short* Kh    = (unsigned short*)(ws + 40 * MB);
  unsigned short* VhT   = (unsigned short*)(ws + 48 * MB);
  unsigned short* attnb = (unsigned short*)(ws + 56 * MB);

  const int n4 = (M_TOT * D_MODEL) / 4;
  cvt_bf16_kernel<<<n4 / 256, 256, 0, stream>>>(q, qb, n4);
  cvt_bf16_kernel<<<n4 / 256, 256, 0, stream>>>(k, kb, n4);
  cvt_bf16_kernel<<<n4 / 256, 256, 0, stream>>>(v, vb, n4);

  dim3 tg(16, 16);
  transpose_cvt<<<tg, 256, 0, stream>>>(wq, wqT, D_MODEL);
  transpose_cvt<<<tg, 256, 0, stream>>>(wk, wkT, D_MODEL);
  transpose_cvt<<<tg, 256, 0, stream>>>(wv, wvT, D_MODEL);
  transpose_cvt<<<tg, 256, 0, stream>>>(wo, woT, D_MODEL);

  dim3 gg(M_TOT / 128, D_MODEL / 128);   // (32, 8)
  gemm_bt<0><<<gg, 256, 0, stream>>>(qb, wqT, (void*)Qh,  M_TOT, D_MODEL, D_MODEL);
  gemm_bt<0><<<gg, 256, 0, stream>>>(kb, wkT, (void*)Kh,  M_TOT, D_MODEL, D_MODEL);
  gemm_bt<2><<<gg, 256, 0, stream>>>(vb, wvT, (void*)VhT, M_TOT, D_MODEL, D_MODEL);

  dim3 ga(SS / 128, BB * NH);            // (16, 32): folded causal pairs
  attn_kernel<<<ga, 256, 0, stream>>>(Qh, Kh, VhT, attnb);

  gemm_bt<1><<<gg, 256, 0, stream>>>(attnb, woT, (void*)out, M_TOT, D_MODEL, D_MODEL);
}

// Round 4
// 239.244 us; speedup vs baseline: 1.1900x; 1.0101x over previous
//
#include <hip/hip_runtime.h>

#define D_MODEL 1024
#define NH 16
#define DK 64
#define BB 2
#define SS 2048
#define M_TOT (BB*SS)

typedef float f32x4 __attribute__((ext_vector_type(4)));
typedef __bf16 bf16x8 __attribute__((ext_vector_type(8)));

__device__ __forceinline__ unsigned short f2bf(float f){
  unsigned int u = __float_as_uint(f);
  unsigned int r = (u + 0x7fffu + ((u >> 16) & 1u)) >> 16;
  return (unsigned short)r;
}

__device__ __forceinline__ void gload_lds16(const void* g, void* l){
  __builtin_amdgcn_global_load_lds((const __attribute__((address_space(1))) void*)g,
                                   (__attribute__((address_space(3))) void*)l,
                                   16, 0, 0);
}

// ---------------- fp32 -> bf16 convert: q,k,v in one dispatch ----------------
__global__ __launch_bounds__(256) void cvt3_bf16(const float* __restrict__ q,
                                                 const float* __restrict__ k,
                                                 const float* __restrict__ v,
                                                 unsigned short* __restrict__ qb,
                                                 unsigned short* __restrict__ kb,
                                                 unsigned short* __restrict__ vb){
  const int which = blockIdx.y;
  const float* in = (which == 0) ? q : (which == 1) ? k : v;
  unsigned short* out = (which == 0) ? qb : (which == 1) ? kb : vb;
  int i = blockIdx.x * 256 + threadIdx.x;
  float4 f = ((const float4*)in)[i];
  ushort4 o;
  o.x = f2bf(f.x); o.y = f2bf(f.y); o.z = f2bf(f.z); o.w = f2bf(f.w);
  ((ushort4*)out)[i] = o;
}

// ------------- fp32 [K][N] -> bf16 [N][K] transpose-convert, 4 mats -------------
__global__ __launch_bounds__(256) void transpose_cvt4(const float* __restrict__ wq,
                                                      const float* __restrict__ wk,
                                                      const float* __restrict__ wv,
                                                      const float* __restrict__ wo,
                                                      unsigned short* __restrict__ WqkvT,
                                                      unsigned short* __restrict__ woT){
  __shared__ float tile[64][65];
  const int which = blockIdx.z;
  const float* w = (which == 0) ? wq : (which == 1) ? wk : (which == 2) ? wv : wo;
  unsigned short* wt = (which == 3) ? woT : (WqkvT + (size_t)which * 1024 * 1024);
  const int N = D_MODEL;
  const int bx = blockIdx.x * 64;
  const int by = blockIdx.y * 64;
  const int t = threadIdx.x;
  #pragma unroll
  for (int i = 0; i < 16; ++i){
    int idx = t + i * 256;
    int r = idx >> 6, c = idx & 63;
    tile[r][c] = w[(size_t)(by + r) * N + bx + c];
  }
  __syncthreads();
  #pragma unroll
  for (int i = 0; i < 16; ++i){
    int idx = t + i * 256;
    int r = idx >> 6, c = idx & 63;
    wt[(size_t)(bx + r) * N + by + c] = f2bf(tile[c][r]);
  }
}

// ---------------- fused QKV projection GEMM ----------------
// WT: [3*1024][1024] bf16 (wq^T|wk^T|wv^T).
// seg 0 -> Qh scatter, seg 1 -> Kh scatter, seg 2 -> VhT transposed store.
__global__ __launch_bounds__(256) void gemm_qkv(const unsigned short* __restrict__ Aq,
                                                const unsigned short* __restrict__ Ak,
                                                const unsigned short* __restrict__ Av,
                                                const unsigned short* __restrict__ WT,
                                                unsigned short* __restrict__ Qh,
                                                unsigned short* __restrict__ Kh,
                                                unsigned short* __restrict__ VhT){
  __shared__ unsigned short Al[2][128 * 32];
  __shared__ unsigned short Bl[2][128 * 32];
  const int tid = threadIdx.x;
  const int wid = tid >> 6, lane = tid & 63;
  const int lr = lane & 15, lg = lane >> 4;
  const int wm = wid >> 1, wn = wid & 1;
  const int bm = blockIdx.x, bn = blockIdx.y;
  const int seg = bn >> 3;
  const unsigned short* A = (seg == 0) ? Aq : (seg == 1) ? Ak : Av;
  const int K = D_MODEL;

  f32x4 acc[4][4];
  #pragma unroll
  for (int i = 0; i < 4; ++i)
    #pragma unroll
    for (int j = 0; j < 4; ++j)
      acc[i][j] = (f32x4){0.f, 0.f, 0.f, 0.f};

  auto stage = [&](int buf, int kt){
    #pragma unroll
    for (int r = 0; r < 2; ++r){
      int vt = tid + r * 256;
      int row = vt >> 2, c8 = (vt & 3) * 8;
      gload_lds16(A  + (size_t)(bm * 128 + row) * K + kt * 32 + c8,
                  &Al[buf][(wid << 9) + r * 2048]);
      gload_lds16(WT + (size_t)(bn * 128 + row) * K + kt * 32 + c8,
                  &Bl[buf][(wid << 9) + r * 2048]);
    }
  };

  stage(0, 0);
  int cur = 0;
  for (int kt = 0; kt < 32; ++kt){
    __syncthreads();
    if (kt + 1 < 32) stage(cur ^ 1, kt + 1);
    bf16x8 af[4], bfr[4];
    #pragma unroll
    for (int i = 0; i < 4; ++i)
      af[i] = *(const bf16x8*)&Al[cur][(wm * 64 + i * 16 + lr) * 32 + lg * 8];
    #pragma unroll
    for (int j = 0; j < 4; ++j)
      bfr[j] = *(const bf16x8*)&Bl[cur][(wn * 64 + j * 16 + lr) * 32 + lg * 8];
    #pragma unroll
    for (int i = 0; i < 4; ++i)
      #pragma unroll
      for (int j = 0; j < 4; ++j)
        acc[i][j] = __builtin_amdgcn_mfma_f32_16x16x32_bf16(af[i], bfr[j], acc[i][j], 0, 0, 0);
    cur ^= 1;
  }

  if (seg < 2){
    unsigned short* O = (seg == 0) ? Qh : Kh;
    #pragma unroll
    for (int i = 0; i < 4; ++i){
      int row0 = bm * 128 + wm * 64 + i * 16 + lg * 4;
      #pragma unroll
      for (int j = 0; j < 4; ++j){
        int colseg = (bn & 7) * 128 + wn * 64 + j * 16 + lr;
        int h = colseg >> 6, dk = colseg & 63;
        #pragma unroll
        for (int p = 0; p < 4; ++p){
          int rowm = row0 + p;
          int b = rowm >> 11, s = rowm & 2047;
          O[((size_t)(b * NH + h) * SS + s) * DK + dk] = f2bf(acc[i][j][p]);
        }
      }
    }
  } else {
    #pragma unroll
    for (int i = 0; i < 4; ++i){
      int row0 = bm * 128 + wm * 64 + i * 16 + lg * 4;
      int b = row0 >> 11, s = row0 & 2047;
      #pragma unroll
      for (int j = 0; j < 4; ++j){
        int colseg = (bn & 7) * 128 + wn * 64 + j * 16 + lr;
        int h = colseg >> 6, dk = colseg & 63;
        ushort4 o4;
        o4.x = f2bf(acc[i][j][0]); o4.y = f2bf(acc[i][j][1]);
        o4.z = f2bf(acc[i][j][2]); o4.w = f2bf(acc[i][j][3]);
        *(ushort4*)&VhT[((size_t)(b * NH + h) * DK + dk) * SS + s] = o4;
      }
    }
  }
}

// ---------------- output projection GEMM (BM=64 for occupancy) ----------------
__global__ __launch_bounds__(256) void gemm_o64(const unsigned short* __restrict__ A,
                                                const unsigned short* __restrict__ Bt,
                                                float* __restrict__ O){
  __shared__ unsigned short Al[2][64 * 32];
  __shared__ unsigned short Bl[2][128 * 32];
  const int tid = threadIdx.x;
  const int wid = tid >> 6, lane = tid & 63;
  const int lr = lane & 15, lg = lane >> 4;
  const int wm = wid >> 1, wn = wid & 1;
  const int bm = blockIdx.x, bn = blockIdx.y;
  const int K = D_MODEL;

  f32x4 acc[2][4];
  #pragma unroll
  for (int i = 0; i < 2; ++i)
    #pragma unroll
    for (int j = 0; j < 4; ++j)
      acc[i][j] = (f32x4){0.f, 0.f, 0.f, 0.f};

  auto stage = [&](int buf, int kt){
    {
      int row = tid >> 2, c8 = (tid & 3) * 8;
      gload_lds16(A + (size_t)(bm * 64 + row) * K + kt * 32 + c8,
                  &Al[buf][wid << 9]);
    }
    #pragma unroll
    for (int r = 0; r < 2; ++r){
      int vt = tid + r * 256;
      int row = vt >> 2, c8 = (vt & 3) * 8;
      gload_lds16(Bt + (size_t)(bn * 128 + row) * K + kt * 32 + c8,
                  &Bl[buf][(wid << 9) + r * 2048]);
    }
  };

  stage(0, 0);
  int cur = 0;
  for (int kt = 0; kt < 32; ++kt){
    __syncthreads();
    if (kt + 1 < 32) stage(cur ^ 1, kt + 1);
    bf16x8 af[2], bfr[4];
    #pragma unroll
    for (int i = 0; i < 2; ++i)
      af[i] = *(const bf16x8*)&Al[cur][(wm * 32 + i * 16 + lr) * 32 + lg * 8];
    #pragma unroll
    for (int j = 0; j < 4; ++j)
      bfr[j] = *(const bf16x8*)&Bl[cur][(wn * 64 + j * 16 + lr) * 32 + lg * 8];
    #pragma unroll
    for (int i = 0; i < 2; ++i)
      #pragma unroll
      for (int j = 0; j < 4; ++j)
        acc[i][j] = __builtin_amdgcn_mfma_f32_16x16x32_bf16(af[i], bfr[j], acc[i][j], 0, 0, 0);
    cur ^= 1;
  }

  #pragma unroll
  for (int i = 0; i < 2; ++i){
    int row0 = bm * 64 + wm * 32 + i * 16 + lg * 4;
    #pragma unroll
    for (int j = 0; j < 4; ++j){
      int col = bn * 128 + wn * 64 + j * 16 + lr;
      #pragma unroll
      for (int p = 0; p < 4; ++p)
        O[(size_t)(row0 + p) * D_MODEL + col] = acc[i][j][p];
    }
  }
}

// ---------------- causal flash attention (round-2-proven inner loop) ----------------
// Grid (bh=32, qt=32): bh on x so bh%8 pins to one XCD (K/V L2 reuse).
// 4 waves x 16 q-rows; fresh K/V fragment loads per tile; no setprio;
// no __syncthreads (per-wave-private P tile only).
__global__ __launch_bounds__(256) void attn_kernel(const unsigned short* __restrict__ Qh,
                                                   const unsigned short* __restrict__ Kh,
                                                   const unsigned short* __restrict__ VhT,
                                                   unsigned short* __restrict__ Oc){
  __shared__ unsigned short Pl[4][16][72];
  const int bh = blockIdx.x, qt = blockIdx.y;
  const int tid = threadIdx.x, wid = tid >> 6, lane = tid & 63;
  const int lr = lane & 15, lg = lane >> 4;
  const int b = bh >> 4, h = bh & 15;
  const size_t kvbase = (size_t)bh * SS * DK;
  const int q0 = qt * 64 + wid * 16;

  const unsigned short* qp = Qh + kvbase + (size_t)(q0 + lr) * DK + lg * 8;
  bf16x8 aq0 = *(const bf16x8*)qp;
  bf16x8 aq1 = *(const bf16x8*)(qp + 32);

  f32x4 o[4];
  #pragma unroll
  for (int df = 0; df < 4; ++df) o[df] = (f32x4){0.f, 0.f, 0.f, 0.f};
  float m[4], ls[4];
  #pragma unroll
  for (int p = 0; p < 4; ++p){ m[p] = -1e30f; ls[p] = 0.f; }

  for (int kt = 0; kt <= qt; ++kt){
    const int k0 = kt * 64;
    // K fragments (A-layout rows) and V^T fragments (B-layout rows)
    bf16x8 bk[4][2], vb[4][2];
    #pragma unroll
    for (int cf = 0; cf < 4; ++cf){
      const unsigned short* kp = Kh + kvbase + (size_t)(k0 + cf * 16 + lr) * DK + lg * 8;
      bk[cf][0] = *(const bf16x8*)kp;
      bk[cf][1] = *(const bf16x8*)(kp + 32);
    }
    #pragma unroll
    for (int df = 0; df < 4; ++df){
      const unsigned short* vp = VhT + kvbase + (size_t)(df * 16 + lr) * SS + k0 + lg * 8;
      vb[df][0] = *(const bf16x8*)vp;
      vb[df][1] = *(const bf16x8*)(vp + 32);
    }
    // scores
    f32x4 sc[4];
    #pragma unroll
    for (int cf = 0; cf < 4; ++cf){
      f32x4 s = (f32x4){0.f, 0.f, 0.f, 0.f};
      s = __builtin_amdgcn_mfma_f32_16x16x32_bf16(aq0, bk[cf][0], s, 0, 0, 0);
      s = __builtin_amdgcn_mfma_f32_16x16x32_bf16(aq1, bk[cf][1], s, 0, 0, 0);
      #pragma unroll
      for (int p = 0; p < 4; ++p) s[p] *= 0.125f;
      sc[cf] = s;
    }
    // causal mask only on the diagonal tile (wave-uniform branch)
    if (kt == qt){
      #pragma unroll
      for (int cf = 0; cf < 4; ++cf){
        int kk = cf * 16 + lr;
        #pragma unroll
        for (int p = 0; p < 4; ++p){
          int qq = wid * 16 + lg * 4 + p;
          if (kk > qq) sc[cf][p] = -1e9f;
        }
      }
    }
    // online softmax (reduce over the 16 lr-lanes)
    float fac[4];
    #pragma unroll
    for (int p = 0; p < 4; ++p){
      float t = fmaxf(fmaxf(sc[0][p], sc[1][p]), fmaxf(sc[2][p], sc[3][p]));
      #pragma unroll
      for (int d = 1; d < 16; d <<= 1) t = fmaxf(t, __shfl_xor(t, d));
      float mn = fmaxf(m[p], t);
      fac[p] = __expf(m[p] - mn);
      m[p] = mn;
    }
    float rs[4] = {0.f, 0.f, 0.f, 0.f};
    #pragma unroll
    for (int cf = 0; cf < 4; ++cf)
      #pragma unroll
      for (int p = 0; p < 4; ++p){
        float e = __expf(sc[cf][p] - m[p]);
        sc[cf][p] = e;
        rs[p] += e;
      }
    #pragma unroll
    for (int p = 0; p < 4; ++p){
      float r = rs[p];
      #pragma unroll
      for (int d = 1; d < 16; d <<= 1) r += __shfl_xor(r, d);
      ls[p] = ls[p] * fac[p] + r;
    }
    // P -> LDS (per-wave private), rescale O
    #pragma unroll
    for (int cf = 0; cf < 4; ++cf)
      #pragma unroll
      for (int p = 0; p < 4; ++p)
        Pl[wid][lg * 4 + p][cf * 16 + lr] = f2bf(sc[cf][p]);
    #pragma unroll
    for (int df = 0; df < 4; ++df)
      #pragma unroll
      for (int p = 0; p < 4; ++p)
        o[df][p] *= fac[p];
    // PV (same-wave LDS dependency; compiler inserts lgkmcnt)
    bf16x8 pa0 = *(const bf16x8*)&Pl[wid][lr][lg * 8];
    bf16x8 pa1 = *(const bf16x8*)&Pl[wid][lr][32 + lg * 8];
    #pragma unroll
    for (int df = 0; df < 4; ++df){
      o[df] = __builtin_amdgcn_mfma_f32_16x16x32_bf16(pa0, vb[df][0], o[df], 0, 0, 0);
      o[df] = __builtin_amdgcn_mfma_f32_16x16x32_bf16(pa1, vb[df][1], o[df], 0, 0, 0);
    }
  }
  // epilogue
  #pragma unroll
  for (int p = 0; p < 4; ++p){
    float inv = 1.0f / ls[p];
    size_t rowbase = ((size_t)b * SS + q0 + lg * 4 + p) * D_MODEL + h * DK;
    #pragma unroll
    for (int df = 0; df < 4; ++df)
      Oc[rowbase + df * 16 + lr] = f2bf(o[df][p] * inv);
  }
}

extern "C" void kernel_launch(void* const* d_in, const int* in_sizes, int n_in,
                              void* d_out, int out_size, void* d_ws, size_t ws_size,
                              hipStream_t stream){
  const float* q  = (const float*)d_in[0];
  const float* k  = (const float*)d_in[1];
  const float* v  = (const float*)d_in[2];
  // d_in[3]: causal mask (deterministic tril) — hardcoded in attn kernel
  const float* wq = (const float*)d_in[4];
  const float* wk = (const float*)d_in[5];
  const float* wv = (const float*)d_in[6];
  const float* wo = (const float*)d_in[7];
  float* out = (float*)d_out;

  char* ws = (char*)d_ws;
  const size_t MB = 1024 * 1024;
  unsigned short* qb     = (unsigned short*)(ws + 0 * MB);
  unsigned short* kb     = (unsigned short*)(ws + 8 * MB);
  unsigned short* vb     = (unsigned short*)(ws + 16 * MB);
  unsigned short* WqkvT  = (unsigned short*)(ws + 24 * MB);   // 6 MB
  unsigned short* woT    = (unsigned short*)(ws + 30 * MB);
  unsigned short* Qh     = (unsigned short*)(ws + 32 * MB);
  unsigned short* Kh     = (unsigned short*)(ws + 40 * MB);
  unsigned short* VhT    = (unsigned short*)(ws + 48 * MB);
  unsigned short* attnb  = (unsigned short*)(ws + 56 * MB);

  const int n4 = (M_TOT * D_MODEL) / 4;   // per tensor
  dim3 gc(n4 / 256, 3);
  cvt3_bf16<<<gc, 256, 0, stream>>>(q, k, v, qb, kb, vb);

  dim3 tg(16, 16, 4);
  transpose_cvt4<<<tg, 256, 0, stream>>>(wq, wk, wv, wo, WqkvT, woT);

  dim3 gqkv(M_TOT / 128, 3 * D_MODEL / 128);   // (32, 24) = 768 blocks
  gemm_qkv<<<gqkv, 256, 0, stream>>>(qb, kb, vb, WqkvT, Qh, Kh, VhT);

  dim3 ga(BB * NH, SS / 64);                   // (32 bh, 32 qt)
  attn_kernel<<<ga, 256, 0, stream>>>(Qh, Kh, VhT, attnb);

  dim3 go(M_TOT / 64, D_MODEL / 128);          // (64, 8) = 512 blocks
  gemm_o64<<<go, 256, 0, stream>>>(attnb, woT, out);
}

// Round 5
// 181.928 us; speedup vs baseline: 1.5649x; 1.3150x over previous
//
#include <hip/hip_runtime.h>

#define D_MODEL 1024
#define NH 16
#define DK 64
#define BB 2
#define SS 2048
#define M_TOT (BB*SS)

typedef float f32x4 __attribute__((ext_vector_type(4)));
typedef float f32x16 __attribute__((ext_vector_type(16)));
typedef __bf16 bf16x8 __attribute__((ext_vector_type(8)));
typedef unsigned int u32;

__device__ __forceinline__ unsigned short f2bf(float f){
  unsigned int u = __float_as_uint(f);
  unsigned int r = (u + 0x7fffu + ((u >> 16) & 1u)) >> 16;
  return (unsigned short)r;
}

__device__ __forceinline__ void gload_lds16(const void* g, void* l){
  __builtin_amdgcn_global_load_lds((const __attribute__((address_space(1))) void*)g,
                                   (__attribute__((address_space(3))) void*)l,
                                   16, 0, 0);
}

// exchange 32-lane halves: x = {lo: a.lo, hi: b.lo}, y = {lo: a.hi, hi: b.hi}
__device__ __forceinline__ void swap_half(u32 a, u32 b, int hi, u32& x, u32& y){
#if __has_builtin(__builtin_amdgcn_permlane32_swap)
  typedef unsigned int uint2v __attribute__((ext_vector_type(2)));
  uint2v r = __builtin_amdgcn_permlane32_swap(a, b, false, false);
  x = r.x; y = r.y;
#else
  u32 as = __shfl_xor(a, 32);
  u32 bs = __shfl_xor(b, 32);
  x = hi ? bs : a;
  y = hi ? b  : as;
#endif
}

// ---------------- fp32 -> bf16 convert: q,k,v in one dispatch ----------------
__global__ __launch_bounds__(256) void cvt3_bf16(const float* __restrict__ q,
                                                 const float* __restrict__ k,
                                                 const float* __restrict__ v,
                                                 unsigned short* __restrict__ qb,
                                                 unsigned short* __restrict__ kb,
                                                 unsigned short* __restrict__ vb){
  const int which = blockIdx.y;
  const float* in = (which == 0) ? q : (which == 1) ? k : v;
  unsigned short* out = (which == 0) ? qb : (which == 1) ? kb : vb;
  int i = blockIdx.x * 256 + threadIdx.x;
  float4 f = ((const float4*)in)[i];
  ushort4 o;
  o.x = f2bf(f.x); o.y = f2bf(f.y); o.z = f2bf(f.z); o.w = f2bf(f.w);
  ((ushort4*)out)[i] = o;
}

// ------------- fp32 [K][N] -> bf16 [N][K] transpose-convert, 4 mats -------------
__global__ __launch_bounds__(256) void transpose_cvt4(const float* __restrict__ wq,
                                                      const float* __restrict__ wk,
                                                      const float* __restrict__ wv,
                                                      const float* __restrict__ wo,
                                                      unsigned short* __restrict__ WqkvT,
                                                      unsigned short* __restrict__ woT){
  __shared__ float tile[64][65];
  const int which = blockIdx.z;
  const float* w = (which == 0) ? wq : (which == 1) ? wk : (which == 2) ? wv : wo;
  unsigned short* wt = (which == 3) ? woT : (WqkvT + (size_t)which * 1024 * 1024);
  const int N = D_MODEL;
  const int bx = blockIdx.x * 64;
  const int by = blockIdx.y * 64;
  const int t = threadIdx.x;
  #pragma unroll
  for (int i = 0; i < 16; ++i){
    int idx = t + i * 256;
    int r = idx >> 6, c = idx & 63;
    tile[r][c] = w[(size_t)(by + r) * N + bx + c];
  }
  __syncthreads();
  #pragma unroll
  for (int i = 0; i < 16; ++i){
    int idx = t + i * 256;
    int r = idx >> 6, c = idx & 63;
    wt[(size_t)(bx + r) * N + by + c] = f2bf(tile[c][r]);
  }
}

// ---------------- fused QKV projection GEMM ----------------
__global__ __launch_bounds__(256) void gemm_qkv(const unsigned short* __restrict__ Aq,
                                                const unsigned short* __restrict__ Ak,
                                                const unsigned short* __restrict__ Av,
                                                const unsigned short* __restrict__ WT,
                                                unsigned short* __restrict__ Qh,
                                                unsigned short* __restrict__ Kh,
                                                unsigned short* __restrict__ VhT){
  __shared__ unsigned short Al[2][128 * 32];
  __shared__ unsigned short Bl[2][128 * 32];
  const int tid = threadIdx.x;
  const int wid = tid >> 6, lane = tid & 63;
  const int lr = lane & 15, lg = lane >> 4;
  const int wm = wid >> 1, wn = wid & 1;
  const int bm = blockIdx.x, bn = blockIdx.y;
  const int seg = bn >> 3;
  const unsigned short* A = (seg == 0) ? Aq : (seg == 1) ? Ak : Av;
  const int K = D_MODEL;

  f32x4 acc[4][4];
  #pragma unroll
  for (int i = 0; i < 4; ++i)
    #pragma unroll
    for (int j = 0; j < 4; ++j)
      acc[i][j] = (f32x4){0.f, 0.f, 0.f, 0.f};

  auto stage = [&](int buf, int kt){
    #pragma unroll
    for (int r = 0; r < 2; ++r){
      int vt = tid + r * 256;
      int row = vt >> 2, c8 = (vt & 3) * 8;
      gload_lds16(A  + (size_t)(bm * 128 + row) * K + kt * 32 + c8,
                  &Al[buf][(wid << 9) + r * 2048]);
      gload_lds16(WT + (size_t)(bn * 128 + row) * K + kt * 32 + c8,
                  &Bl[buf][(wid << 9) + r * 2048]);
    }
  };

  stage(0, 0);
  int cur = 0;
  for (int kt = 0; kt < 32; ++kt){
    __syncthreads();
    if (kt + 1 < 32) stage(cur ^ 1, kt + 1);
    bf16x8 af[4], bfr[4];
    #pragma unroll
    for (int i = 0; i < 4; ++i)
      af[i] = *(const bf16x8*)&Al[cur][(wm * 64 + i * 16 + lr) * 32 + lg * 8];
    #pragma unroll
    for (int j = 0; j < 4; ++j)
      bfr[j] = *(const bf16x8*)&Bl[cur][(wn * 64 + j * 16 + lr) * 32 + lg * 8];
    #pragma unroll
    for (int i = 0; i < 4; ++i)
      #pragma unroll
      for (int j = 0; j < 4; ++j)
        acc[i][j] = __builtin_amdgcn_mfma_f32_16x16x32_bf16(af[i], bfr[j], acc[i][j], 0, 0, 0);
    cur ^= 1;
  }

  if (seg < 2){
    unsigned short* O = (seg == 0) ? Qh : Kh;
    #pragma unroll
    for (int i = 0; i < 4; ++i){
      int row0 = bm * 128 + wm * 64 + i * 16 + lg * 4;
      #pragma unroll
      for (int j = 0; j < 4; ++j){
        int colseg = (bn & 7) * 128 + wn * 64 + j * 16 + lr;
        int h = colseg >> 6, dk = colseg & 63;
        #pragma unroll
        for (int p = 0; p < 4; ++p){
          int rowm = row0 + p;
          int b = rowm >> 11, s = rowm & 2047;
          O[((size_t)(b * NH + h) * SS + s) * DK + dk] = f2bf(acc[i][j][p]);
        }
      }
    }
  } else {
    #pragma unroll
    for (int i = 0; i < 4; ++i){
      int row0 = bm * 128 + wm * 64 + i * 16 + lg * 4;
      int b = row0 >> 11, s = row0 & 2047;
      #pragma unroll
      for (int j = 0; j < 4; ++j){
        int colseg = (bn & 7) * 128 + wn * 64 + j * 16 + lr;
        int h = colseg >> 6, dk = colseg & 63;
        ushort4 o4;
        o4.x = f2bf(acc[i][j][0]); o4.y = f2bf(acc[i][j][1]);
        o4.z = f2bf(acc[i][j][2]); o4.w = f2bf(acc[i][j][3]);
        *(ushort4*)&VhT[((size_t)(b * NH + h) * DK + dk) * SS + s] = o4;
      }
    }
  }
}

// ---------------- output projection GEMM (BM=64 for occupancy) ----------------
__global__ __launch_bounds__(256) void gemm_o64(const unsigned short* __restrict__ A,
                                                const unsigned short* __restrict__ Bt,
                                                float* __restrict__ O){
  __shared__ unsigned short Al[2][64 * 32];
  __shared__ unsigned short Bl[2][128 * 32];
  const int tid = threadIdx.x;
  const int wid = tid >> 6, lane = tid & 63;
  const int lr = lane & 15, lg = lane >> 4;
  const int wm = wid >> 1, wn = wid & 1;
  const int bm = blockIdx.x, bn = blockIdx.y;
  const int K = D_MODEL;

  f32x4 acc[2][4];
  #pragma unroll
  for (int i = 0; i < 2; ++i)
    #pragma unroll
    for (int j = 0; j < 4; ++j)
      acc[i][j] = (f32x4){0.f, 0.f, 0.f, 0.f};

  auto stage = [&](int buf, int kt){
    {
      int row = tid >> 2, c8 = (tid & 3) * 8;
      gload_lds16(A + (size_t)(bm * 64 + row) * K + kt * 32 + c8,
                  &Al[buf][wid << 9]);
    }
    #pragma unroll
    for (int r = 0; r < 2; ++r){
      int vt = tid + r * 256;
      int row = vt >> 2, c8 = (vt & 3) * 8;
      gload_lds16(Bt + (size_t)(bn * 128 + row) * K + kt * 32 + c8,
                  &Bl[buf][(wid << 9) + r * 2048]);
    }
  };

  stage(0, 0);
  int cur = 0;
  for (int kt = 0; kt < 32; ++kt){
    __syncthreads();
    if (kt + 1 < 32) stage(cur ^ 1, kt + 1);
    bf16x8 af[2], bfr[4];
    #pragma unroll
    for (int i = 0; i < 2; ++i)
      af[i] = *(const bf16x8*)&Al[cur][(wm * 32 + i * 16 + lr) * 32 + lg * 8];
    #pragma unroll
    for (int j = 0; j < 4; ++j)
      bfr[j] = *(const bf16x8*)&Bl[cur][(wn * 64 + j * 16 + lr) * 32 + lg * 8];
    #pragma unroll
    for (int i = 0; i < 2; ++i)
      #pragma unroll
      for (int j = 0; j < 4; ++j)
        acc[i][j] = __builtin_amdgcn_mfma_f32_16x16x32_bf16(af[i], bfr[j], acc[i][j], 0, 0, 0);
    cur ^= 1;
  }

  #pragma unroll
  for (int i = 0; i < 2; ++i){
    int row0 = bm * 64 + wm * 32 + i * 16 + lg * 4;
    #pragma unroll
    for (int j = 0; j < 4; ++j){
      int col = bn * 128 + wn * 64 + j * 16 + lr;
      #pragma unroll
      for (int p = 0; p < 4; ++p)
        O[(size_t)(row0 + p) * D_MODEL + col] = acc[i][j][p];
    }
  }
}

// ---------------- causal flash attention: swapped QK^T, in-register softmax ----------------
// 32x32x16 MFMA. Per wave: 32 q-rows, K-tiles of 32 keys.
// S^T[k][q] = mfma(A=K, B=Q): lane holds 16 P-values of q-column (lane&31);
// k-reduce = 15 VALU + 1 shfl_xor(32). P->bf16 via cvt_pk + half-swap (T12).
// PV: O^T[d][q] = mfma(A=V^T, B=P^T). No LDS, no barriers.
__global__ __launch_bounds__(256) void attn_kernel(const unsigned short* __restrict__ Qh,
                                                   const unsigned short* __restrict__ Kh,
                                                   const unsigned short* __restrict__ VhT,
                                                   unsigned short* __restrict__ Oc){
  const int bh = blockIdx.x;                 // bh%8 -> XCD stickiness (K/V L2 reuse)
  const int tid = threadIdx.x, wid = tid >> 6, lane = tid & 63;
  const int ln = lane & 31, hi = lane >> 5;
  const int b = bh >> 4, h = bh & 15;
  const size_t kvbase = (size_t)bh * SS * DK;
  const int qt = blockIdx.y * 4 + wid;       // q-tile 0..63 (32 rows each)
  const int q0 = qt * 32;

  // Q B-fragments (persistent): col q = ln, d-slice c: d = c*16 + hi*8 + j
  const unsigned short* qp = Qh + kvbase + (size_t)(q0 + ln) * DK + hi * 8;
  bf16x8 qb0 = *(const bf16x8*)(qp);
  bf16x8 qb1 = *(const bf16x8*)(qp + 16);
  bf16x8 qb2 = *(const bf16x8*)(qp + 32);
  bf16x8 qb3 = *(const bf16x8*)(qp + 48);

  f32x16 oa0 = {0,0,0,0,0,0,0,0,0,0,0,0,0,0,0,0};   // O^T d 0..31
  f32x16 oa1 = {0,0,0,0,0,0,0,0,0,0,0,0,0,0,0,0};   // O^T d 32..63
  float m = -1e30f, ls = 0.f;

  for (int kt = 0; kt <= qt; ++kt){
    const int k0 = kt * 32;
    // K A-fragments: row k = ln, d-slice c
    const unsigned short* kp = Kh + kvbase + (size_t)(k0 + ln) * DK + hi * 8;
    bf16x8 ka0 = *(const bf16x8*)(kp);
    bf16x8 ka1 = *(const bf16x8*)(kp + 16);
    bf16x8 ka2 = *(const bf16x8*)(kp + 32);
    bf16x8 ka3 = *(const bf16x8*)(kp + 48);
    // V^T A-fragments: row d = dt*32 + ln, k-slice ks: s = k0 + ks*16 + hi*8 + j
    const unsigned short* vp = VhT + kvbase + (size_t)ln * SS + k0 + hi * 8;
    bf16x8 va00 = *(const bf16x8*)(vp);
    bf16x8 va01 = *(const bf16x8*)(vp + 16);
    bf16x8 va10 = *(const bf16x8*)(vp + (size_t)32 * SS);
    bf16x8 va11 = *(const bf16x8*)(vp + (size_t)32 * SS + 16);

    // S^T = K * Q^T  (chained over 4 d-slices)
    f32x16 st = {0,0,0,0,0,0,0,0,0,0,0,0,0,0,0,0};
    st = __builtin_amdgcn_mfma_f32_32x32x16_bf16(ka0, qb0, st, 0, 0, 0);
    st = __builtin_amdgcn_mfma_f32_32x32x16_bf16(ka1, qb1, st, 0, 0, 0);
    st = __builtin_amdgcn_mfma_f32_32x32x16_bf16(ka2, qb2, st, 0, 0, 0);
    st = __builtin_amdgcn_mfma_f32_32x32x16_bf16(ka3, qb3, st, 0, 0, 0);

    #pragma unroll
    for (int r = 0; r < 16; ++r) st[r] *= 0.125f;
    if (kt == qt){   // diagonal: local k = (r&3)+8*(r>>2)+4*hi vs local q = ln
      #pragma unroll
      for (int r = 0; r < 16; ++r){
        int kg = (r & 3) + 8 * (r >> 2) + 4 * hi;
        if (kg > ln) st[r] = -1e9f;
      }
    }
    // in-register row max (16 values) + partner half
    float t = st[0];
    #pragma unroll
    for (int r = 1; r < 16; ++r) t = fmaxf(t, st[r]);
    t = fmaxf(t, __shfl_xor(t, 32));
    float mn = fmaxf(m, t);
    float fac = __expf(m - mn);
    m = mn;
    float rs = 0.f;
    #pragma unroll
    for (int r = 0; r < 16; ++r){
      float e = __expf(st[r] - mn);
      st[r] = e;
      rs += e;
    }
    rs += __shfl_xor(rs, 32);
    ls = ls * fac + rs;
    #pragma unroll
    for (int r = 0; r < 16; ++r){ oa0[r] *= fac; oa1[r] *= fac; }

    // P^T -> bf16 B-fragments: cvt_pk pairs then half-swaps
    u32 c0, c1, c2, c3, c4, c5, c6, c7;
    asm("v_cvt_pk_bf16_f32 %0, %1, %2" : "=v"(c0) : "v"(st[0]),  "v"(st[1]));
    asm("v_cvt_pk_bf16_f32 %0, %1, %2" : "=v"(c1) : "v"(st[2]),  "v"(st[3]));
    asm("v_cvt_pk_bf16_f32 %0, %1, %2" : "=v"(c2) : "v"(st[4]),  "v"(st[5]));
    asm("v_cvt_pk_bf16_f32 %0, %1, %2" : "=v"(c3) : "v"(st[6]),  "v"(st[7]));
    asm("v_cvt_pk_bf16_f32 %0, %1, %2" : "=v"(c4) : "v"(st[8]),  "v"(st[9]));
    asm("v_cvt_pk_bf16_f32 %0, %1, %2" : "=v"(c5) : "v"(st[10]), "v"(st[11]));
    asm("v_cvt_pk_bf16_f32 %0, %1, %2" : "=v"(c6) : "v"(st[12]), "v"(st[13]));
    asm("v_cvt_pk_bf16_f32 %0, %1, %2" : "=v"(c7) : "v"(st[14]), "v"(st[15]));
    u32 pb0w[4], pb1w[4];
    swap_half(c0, c2, hi, pb0w[0], pb0w[2]);
    swap_half(c1, c3, hi, pb0w[1], pb0w[3]);
    swap_half(c4, c6, hi, pb1w[0], pb1w[2]);
    swap_half(c5, c7, hi, pb1w[1], pb1w[3]);
    bf16x8 pb0, pb1;
    __builtin_memcpy(&pb0, pb0w, 16);
    __builtin_memcpy(&pb1, pb1w, 16);

    // O^T += V^T * P^T
    oa0 = __builtin_amdgcn_mfma_f32_32x32x16_bf16(va00, pb0, oa0, 0, 0, 0);
    oa0 = __builtin_amdgcn_mfma_f32_32x32x16_bf16(va01, pb1, oa0, 0, 0, 0);
    oa1 = __builtin_amdgcn_mfma_f32_32x32x16_bf16(va10, pb0, oa1, 0, 0, 0);
    oa1 = __builtin_amdgcn_mfma_f32_32x32x16_bf16(va11, pb1, oa1, 0, 0, 0);
  }

  // epilogue: O^T[d][q] -> Oc[b][s=q0+ln][h*64 + d], d = dt*32 + 8g + 4hi + {0..3}
  float inv = 1.0f / ls;
  size_t rowbase = ((size_t)b * SS + q0 + ln) * D_MODEL + h * DK;
  #pragma unroll
  for (int g = 0; g < 4; ++g){
    ushort4 o4;
    o4.x = f2bf(oa0[4*g + 0] * inv); o4.y = f2bf(oa0[4*g + 1] * inv);
    o4.z = f2bf(oa0[4*g + 2] * inv); o4.w = f2bf(oa0[4*g + 3] * inv);
    *(ushort4*)&Oc[rowbase + 8*g + 4*hi] = o4;
  }
  #pragma unroll
  for (int g = 0; g < 4; ++g){
    ushort4 o4;
    o4.x = f2bf(oa1[4*g + 0] * inv); o4.y = f2bf(oa1[4*g + 1] * inv);
    o4.z = f2bf(oa1[4*g + 2] * inv); o4.w = f2bf(oa1[4*g + 3] * inv);
    *(ushort4*)&Oc[rowbase + 32 + 8*g + 4*hi] = o4;
  }
}

extern "C" void kernel_launch(void* const* d_in, const int* in_sizes, int n_in,
                              void* d_out, int out_size, void* d_ws, size_t ws_size,
                              hipStream_t stream){
  const float* q  = (const float*)d_in[0];
  const float* k  = (const float*)d_in[1];
  const float* v  = (const float*)d_in[2];
  // d_in[3]: causal mask (deterministic tril) — hardcoded in attn kernel
  const float* wq = (const float*)d_in[4];
  const float* wk = (const float*)d_in[5];
  const float* wv = (const float*)d_in[6];
  const float* wo = (const float*)d_in[7];
  float* out = (float*)d_out;

  char* ws = (char*)d_ws;
  const size_t MB = 1024 * 1024;
  unsigned short* qb     = (unsigned short*)(ws + 0 * MB);
  unsigned short* kb     = (unsigned short*)(ws + 8 * MB);
  unsigned short* vb     = (unsigned short*)(ws + 16 * MB);
  unsigned short* WqkvT  = (unsigned short*)(ws + 24 * MB);   // 6 MB
  unsigned short* woT    = (unsigned short*)(ws + 30 * MB);
  unsigned short* Qh     = (unsigned short*)(ws + 32 * MB);
  unsigned short* Kh     = (unsigned short*)(ws + 40 * MB);
  unsigned short* VhT    = (unsigned short*)(ws + 48 * MB);
  unsigned short* attnb  = (unsigned short*)(ws + 56 * MB);

  const int n4 = (M_TOT * D_MODEL) / 4;   // per tensor
  dim3 gc(n4 / 256, 3);
  cvt3_bf16<<<gc, 256, 0, stream>>>(q, k, v, qb, kb, vb);

  dim3 tg(16, 16, 4);
  transpose_cvt4<<<tg, 256, 0, stream>>>(wq, wk, wv, wo, WqkvT, woT);

  dim3 gqkv(M_TOT / 128, 3 * D_MODEL / 128);   // (32, 24) = 768 blocks
  gemm_qkv<<<gqkv, 256, 0, stream>>>(qb, kb, vb, WqkvT, Qh, Kh, VhT);

  dim3 ga(BB * NH, SS / 128);                  // (32 bh, 16): qt = y*4 + wid
  attn_kernel<<<ga, 256, 0, stream>>>(Qh, Kh, VhT, attnb);

  dim3 go(M_TOT / 64, D_MODEL / 128);          // (64, 8) = 512 blocks
  gemm_o64<<<go, 256, 0, stream>>>(attnb, woT, out);
}

// Round 6
// 164.794 us; speedup vs baseline: 1.7276x; 1.1040x over previous
//
#include <hip/hip_runtime.h>

#define D_MODEL 1024
#define NH 16
#define DK 64
#define BB 2
#define SS 2048
#define M_TOT (BB*SS)

typedef float f32x4 __attribute__((ext_vector_type(4)));
typedef float f32x16 __attribute__((ext_vector_type(16)));
typedef __bf16 bf16x8 __attribute__((ext_vector_type(8)));
typedef unsigned int u32;

__device__ __forceinline__ unsigned short f2bf(float f){
  unsigned int u = __float_as_uint(f);
  unsigned int r = (u + 0x7fffu + ((u >> 16) & 1u)) >> 16;
  return (unsigned short)r;
}

__device__ __forceinline__ void gload_lds16(const void* g, void* l){
  __builtin_amdgcn_global_load_lds((const __attribute__((address_space(1))) void*)g,
                                   (__attribute__((address_space(3))) void*)l,
                                   16, 0, 0);
}

// exchange 32-lane halves: x = {lo: a.lo, hi: b.lo}, y = {lo: a.hi, hi: b.hi}
__device__ __forceinline__ void swap_half(u32 a, u32 b, int hi, u32& x, u32& y){
#if __has_builtin(__builtin_amdgcn_permlane32_swap)
  typedef unsigned int uint2v __attribute__((ext_vector_type(2)));
  uint2v r = __builtin_amdgcn_permlane32_swap(a, b, false, false);
  x = r.x; y = r.y;
#else
  u32 as = __shfl_xor(a, 32);
  u32 bs = __shfl_xor(b, 32);
  x = hi ? bs : a;
  y = hi ? b  : as;
#endif
}

// ---------------- fp32 -> bf16 convert: q,k,v in one dispatch ----------------
__global__ __launch_bounds__(256) void cvt3_bf16(const float* __restrict__ q,
                                                 const float* __restrict__ k,
                                                 const float* __restrict__ v,
                                                 unsigned short* __restrict__ qb,
                                                 unsigned short* __restrict__ kb,
                                                 unsigned short* __restrict__ vb){
  const int which = blockIdx.y;
  const float* in = (which == 0) ? q : (which == 1) ? k : v;
  unsigned short* out = (which == 0) ? qb : (which == 1) ? kb : vb;
  int i = blockIdx.x * 256 + threadIdx.x;
  float4 f = ((const float4*)in)[i];
  ushort4 o;
  o.x = f2bf(f.x); o.y = f2bf(f.y); o.z = f2bf(f.z); o.w = f2bf(f.w);
  ((ushort4*)out)[i] = o;
}

// ------------- fp32 [K][N] -> bf16 [N][K] transpose-convert, 4 mats -------------
__global__ __launch_bounds__(256) void transpose_cvt4(const float* __restrict__ wq,
                                                      const float* __restrict__ wk,
                                                      const float* __restrict__ wv,
                                                      const float* __restrict__ wo,
                                                      unsigned short* __restrict__ WqkvT,
                                                      unsigned short* __restrict__ woT){
  __shared__ float tile[64][65];
  const int which = blockIdx.z;
  const float* w = (which == 0) ? wq : (which == 1) ? wk : (which == 2) ? wv : wo;
  unsigned short* wt = (which == 3) ? woT : (WqkvT + (size_t)which * 1024 * 1024);
  const int N = D_MODEL;
  const int bx = blockIdx.x * 64;
  const int by = blockIdx.y * 64;
  const int t = threadIdx.x;
  #pragma unroll
  for (int i = 0; i < 16; ++i){
    int idx = t + i * 256;
    int r = idx >> 6, c = idx & 63;
    tile[r][c] = w[(size_t)(by + r) * N + bx + c];
  }
  __syncthreads();
  #pragma unroll
  for (int i = 0; i < 16; ++i){
    int idx = t + i * 256;
    int r = idx >> 6, c = idx & 63;
    wt[(size_t)(bx + r) * N + by + c] = f2bf(tile[c][r]);
  }
}

// ---------------- fused QKV projection GEMM ----------------
__global__ __launch_bounds__(256) void gemm_qkv(const unsigned short* __restrict__ Aq,
                                                const unsigned short* __restrict__ Ak,
                                                const unsigned short* __restrict__ Av,
                                                const unsigned short* __restrict__ WT,
                                                unsigned short* __restrict__ Qh,
                                                unsigned short* __restrict__ Kh,
                                                unsigned short* __restrict__ VhT){
  __shared__ unsigned short Al[2][128 * 32];
  __shared__ unsigned short Bl[2][128 * 32];
  const int tid = threadIdx.x;
  const int wid = tid >> 6, lane = tid & 63;
  const int lr = lane & 15, lg = lane >> 4;
  const int wm = wid >> 1, wn = wid & 1;
  const int bm = blockIdx.x, bn = blockIdx.y;
  const int seg = bn >> 3;
  const unsigned short* A = (seg == 0) ? Aq : (seg == 1) ? Ak : Av;
  const int K = D_MODEL;

  f32x4 acc[4][4];
  #pragma unroll
  for (int i = 0; i < 4; ++i)
    #pragma unroll
    for (int j = 0; j < 4; ++j)
      acc[i][j] = (f32x4){0.f, 0.f, 0.f, 0.f};

  auto stage = [&](int buf, int kt){
    #pragma unroll
    for (int r = 0; r < 2; ++r){
      int vt = tid + r * 256;
      int row = vt >> 2, c8 = (vt & 3) * 8;
      gload_lds16(A  + (size_t)(bm * 128 + row) * K + kt * 32 + c8,
                  &Al[buf][(wid << 9) + r * 2048]);
      gload_lds16(WT + (size_t)(bn * 128 + row) * K + kt * 32 + c8,
                  &Bl[buf][(wid << 9) + r * 2048]);
    }
  };

  stage(0, 0);
  int cur = 0;
  for (int kt = 0; kt < 32; ++kt){
    __syncthreads();
    if (kt + 1 < 32) stage(cur ^ 1, kt + 1);
    bf16x8 af[4], bfr[4];
    #pragma unroll
    for (int i = 0; i < 4; ++i)
      af[i] = *(const bf16x8*)&Al[cur][(wm * 64 + i * 16 + lr) * 32 + lg * 8];
    #pragma unroll
    for (int j = 0; j < 4; ++j)
      bfr[j] = *(const bf16x8*)&Bl[cur][(wn * 64 + j * 16 + lr) * 32 + lg * 8];
    #pragma unroll
    for (int i = 0; i < 4; ++i)
      #pragma unroll
      for (int j = 0; j < 4; ++j)
        acc[i][j] = __builtin_amdgcn_mfma_f32_16x16x32_bf16(af[i], bfr[j], acc[i][j], 0, 0, 0);
    cur ^= 1;
  }

  if (seg < 2){
    unsigned short* O = (seg == 0) ? Qh : Kh;
    #pragma unroll
    for (int i = 0; i < 4; ++i){
      int row0 = bm * 128 + wm * 64 + i * 16 + lg * 4;
      #pragma unroll
      for (int j = 0; j < 4; ++j){
        int colseg = (bn & 7) * 128 + wn * 64 + j * 16 + lr;
        int h = colseg >> 6, dk = colseg & 63;
        #pragma unroll
        for (int p = 0; p < 4; ++p){
          int rowm = row0 + p;
          int b = rowm >> 11, s = rowm & 2047;
          O[((size_t)(b * NH + h) * SS + s) * DK + dk] = f2bf(acc[i][j][p]);
        }
      }
    }
  } else {
    #pragma unroll
    for (int i = 0; i < 4; ++i){
      int row0 = bm * 128 + wm * 64 + i * 16 + lg * 4;
      int b = row0 >> 11, s = row0 & 2047;
      #pragma unroll
      for (int j = 0; j < 4; ++j){
        int colseg = (bn & 7) * 128 + wn * 64 + j * 16 + lr;
        int h = colseg >> 6, dk = colseg & 63;
        ushort4 o4;
        o4.x = f2bf(acc[i][j][0]); o4.y = f2bf(acc[i][j][1]);
        o4.z = f2bf(acc[i][j][2]); o4.w = f2bf(acc[i][j][3]);
        *(ushort4*)&VhT[((size_t)(b * NH + h) * DK + dk) * SS + s] = o4;
      }
    }
  }
}

// ---------------- output projection GEMM (BM=64 for occupancy) ----------------
__global__ __launch_bounds__(256) void gemm_o64(const unsigned short* __restrict__ A,
                                                const unsigned short* __restrict__ Bt,
                                                float* __restrict__ O){
  __shared__ unsigned short Al[2][64 * 32];
  __shared__ unsigned short Bl[2][128 * 32];
  const int tid = threadIdx.x;
  const int wid = tid >> 6, lane = tid & 63;
  const int lr = lane & 15, lg = lane >> 4;
  const int wm = wid >> 1, wn = wid & 1;
  const int bm = blockIdx.x, bn = blockIdx.y;
  const int K = D_MODEL;

  f32x4 acc[2][4];
  #pragma unroll
  for (int i = 0; i < 2; ++i)
    #pragma unroll
    for (int j = 0; j < 4; ++j)
      acc[i][j] = (f32x4){0.f, 0.f, 0.f, 0.f};

  auto stage = [&](int buf, int kt){
    {
      int row = tid >> 2, c8 = (tid & 3) * 8;
      gload_lds16(A + (size_t)(bm * 64 + row) * K + kt * 32 + c8,
                  &Al[buf][wid << 9]);
    }
    #pragma unroll
    for (int r = 0; r < 2; ++r){
      int vt = tid + r * 256;
      int row = vt >> 2, c8 = (vt & 3) * 8;
      gload_lds16(Bt + (size_t)(bn * 128 + row) * K + kt * 32 + c8,
                  &Bl[buf][(wid << 9) + r * 2048]);
    }
  };

  stage(0, 0);
  int cur = 0;
  for (int kt = 0; kt < 32; ++kt){
    __syncthreads();
    if (kt + 1 < 32) stage(cur ^ 1, kt + 1);
    bf16x8 af[2], bfr[4];
    #pragma unroll
    for (int i = 0; i < 2; ++i)
      af[i] = *(const bf16x8*)&Al[cur][(wm * 32 + i * 16 + lr) * 32 + lg * 8];
    #pragma unroll
    for (int j = 0; j < 4; ++j)
      bfr[j] = *(const bf16x8*)&Bl[cur][(wn * 64 + j * 16 + lr) * 32 + lg * 8];
    #pragma unroll
    for (int i = 0; i < 2; ++i)
      #pragma unroll
      for (int j = 0; j < 4; ++j)
        acc[i][j] = __builtin_amdgcn_mfma_f32_16x16x32_bf16(af[i], bfr[j], acc[i][j], 0, 0, 0);
    cur ^= 1;
  }

  #pragma unroll
  for (int i = 0; i < 2; ++i){
    int row0 = bm * 64 + wm * 32 + i * 16 + lg * 4;
    #pragma unroll
    for (int j = 0; j < 4; ++j){
      int col = bn * 128 + wn * 64 + j * 16 + lr;
      #pragma unroll
      for (int p = 0; p < 4; ++p)
        O[(size_t)(row0 + p) * D_MODEL + col] = acc[i][j][p];
    }
  }
}

// ---------------- causal flash attention: swapped QK^T + split-K across waves ----------------
// Grid (bh=32, 64): qt = 63 - blockIdx.y (LPT, longest first); 4 waves split the
// K-range (kt = wid, wid+4, ...) of ONE 32-row q-tile -> max 16 steps/wave.
// Waves 1-3 write partial (m, ls, O^T) to LDS (f32, conflict-free layout);
// wave 0 merges: O* = sum_w exp(m_w - m*) O_w. Empty waves contribute fac=0.
__global__ __launch_bounds__(256) void attn_kernel(const unsigned short* __restrict__ Qh,
                                                   const unsigned short* __restrict__ Kh,
                                                   const unsigned short* __restrict__ VhT,
                                                   unsigned short* __restrict__ Oc){
  __shared__ float oL[3][32][64];   // [wave-1][acc reg][lane]
  __shared__ float mL[3][32];
  __shared__ float lsL[3][32];
  const int bh = blockIdx.x;                 // bh%8 -> XCD stickiness (K/V L2 reuse)
  const int qt = 63 - blockIdx.y;            // LPT: longest blocks dispatched first
  const int tid = threadIdx.x, wid = tid >> 6, lane = tid & 63;
  const int ln = lane & 31, hi = lane >> 5;
  const int b = bh >> 4, h = bh & 15;
  const size_t kvbase = (size_t)bh * SS * DK;
  const int q0 = qt * 32;

  // Q B-fragments (persistent): col q = ln, d-slice c: d = c*16 + hi*8 + j
  const unsigned short* qp = Qh + kvbase + (size_t)(q0 + ln) * DK + hi * 8;
  bf16x8 qb0 = *(const bf16x8*)(qp);
  bf16x8 qb1 = *(const bf16x8*)(qp + 16);
  bf16x8 qb2 = *(const bf16x8*)(qp + 32);
  bf16x8 qb3 = *(const bf16x8*)(qp + 48);

  f32x16 oa0 = {0,0,0,0,0,0,0,0,0,0,0,0,0,0,0,0};   // O^T d 0..31 (partial)
  f32x16 oa1 = {0,0,0,0,0,0,0,0,0,0,0,0,0,0,0,0};   // O^T d 32..63 (partial)
  float m = -1e30f, ls = 0.f;

  for (int kt = wid; kt <= qt; kt += 4){
    const int k0 = kt * 32;
    // K A-fragments: row k = ln, d-slice c
    const unsigned short* kp = Kh + kvbase + (size_t)(k0 + ln) * DK + hi * 8;
    bf16x8 ka0 = *(const bf16x8*)(kp);
    bf16x8 ka1 = *(const bf16x8*)(kp + 16);
    bf16x8 ka2 = *(const bf16x8*)(kp + 32);
    bf16x8 ka3 = *(const bf16x8*)(kp + 48);
    // V^T A-fragments: row d = dt*32 + ln, k-slice ks: s = k0 + ks*16 + hi*8 + j
    const unsigned short* vp = VhT + kvbase + (size_t)ln * SS + k0 + hi * 8;
    bf16x8 va00 = *(const bf16x8*)(vp);
    bf16x8 va01 = *(const bf16x8*)(vp + 16);
    bf16x8 va10 = *(const bf16x8*)(vp + (size_t)32 * SS);
    bf16x8 va11 = *(const bf16x8*)(vp + (size_t)32 * SS + 16);

    // S^T = K * Q^T  (chained over 4 d-slices)
    f32x16 st = {0,0,0,0,0,0,0,0,0,0,0,0,0,0,0,0};
    st = __builtin_amdgcn_mfma_f32_32x32x16_bf16(ka0, qb0, st, 0, 0, 0);
    st = __builtin_amdgcn_mfma_f32_32x32x16_bf16(ka1, qb1, st, 0, 0, 0);
    st = __builtin_amdgcn_mfma_f32_32x32x16_bf16(ka2, qb2, st, 0, 0, 0);
    st = __builtin_amdgcn_mfma_f32_32x32x16_bf16(ka3, qb3, st, 0, 0, 0);

    #pragma unroll
    for (int r = 0; r < 16; ++r) st[r] *= 0.125f;
    if (kt == qt){   // diagonal: local k = (r&3)+8*(r>>2)+4*hi vs local q = ln
      #pragma unroll
      for (int r = 0; r < 16; ++r){
        int kg = (r & 3) + 8 * (r >> 2) + 4 * hi;
        if (kg > ln) st[r] = -1e9f;
      }
    }
    // in-register row max (16 values) + partner half
    float t = st[0];
    #pragma unroll
    for (int r = 1; r < 16; ++r) t = fmaxf(t, st[r]);
    t = fmaxf(t, __shfl_xor(t, 32));
    float mn = fmaxf(m, t);
    float fac = __expf(m - mn);
    m = mn;
    float rs = 0.f;
    #pragma unroll
    for (int r = 0; r < 16; ++r){
      float e = __expf(st[r] - mn);
      st[r] = e;
      rs += e;
    }
    rs += __shfl_xor(rs, 32);
    ls = ls * fac + rs;
    #pragma unroll
    for (int r = 0; r < 16; ++r){ oa0[r] *= fac; oa1[r] *= fac; }

    // P^T -> bf16 B-fragments: cvt_pk pairs then half-swaps
    u32 c0, c1, c2, c3, c4, c5, c6, c7;
    asm("v_cvt_pk_bf16_f32 %0, %1, %2" : "=v"(c0) : "v"(st[0]),  "v"(st[1]));
    asm("v_cvt_pk_bf16_f32 %0, %1, %2" : "=v"(c1) : "v"(st[2]),  "v"(st[3]));
    asm("v_cvt_pk_bf16_f32 %0, %1, %2" : "=v"(c2) : "v"(st[4]),  "v"(st[5]));
    asm("v_cvt_pk_bf16_f32 %0, %1, %2" : "=v"(c3) : "v"(st[6]),  "v"(st[7]));
    asm("v_cvt_pk_bf16_f32 %0, %1, %2" : "=v"(c4) : "v"(st[8]),  "v"(st[9]));
    asm("v_cvt_pk_bf16_f32 %0, %1, %2" : "=v"(c5) : "v"(st[10]), "v"(st[11]));
    asm("v_cvt_pk_bf16_f32 %0, %1, %2" : "=v"(c6) : "v"(st[12]), "v"(st[13]));
    asm("v_cvt_pk_bf16_f32 %0, %1, %2" : "=v"(c7) : "v"(st[14]), "v"(st[15]));
    u32 pb0w[4], pb1w[4];
    swap_half(c0, c2, hi, pb0w[0], pb0w[2]);
    swap_half(c1, c3, hi, pb0w[1], pb0w[3]);
    swap_half(c4, c6, hi, pb1w[0], pb1w[2]);
    swap_half(c5, c7, hi, pb1w[1], pb1w[3]);
    bf16x8 pb0, pb1;
    __builtin_memcpy(&pb0, pb0w, 16);
    __builtin_memcpy(&pb1, pb1w, 16);

    // O^T += V^T * P^T
    oa0 = __builtin_amdgcn_mfma_f32_32x32x16_bf16(va00, pb0, oa0, 0, 0, 0);
    oa0 = __builtin_amdgcn_mfma_f32_32x32x16_bf16(va01, pb1, oa0, 0, 0, 0);
    oa1 = __builtin_amdgcn_mfma_f32_32x32x16_bf16(va10, pb0, oa1, 0, 0, 0);
    oa1 = __builtin_amdgcn_mfma_f32_32x32x16_bf16(va11, pb1, oa1, 0, 0, 0);
  }

  // ---- cross-wave combine ----
  if (wid > 0){
    const int w = wid - 1;
    #pragma unroll
    for (int r = 0; r < 16; ++r){
      oL[w][r][lane]      = oa0[r];
      oL[w][16 + r][lane] = oa1[r];
    }
    if (hi == 0){ mL[w][ln] = m; lsL[w][ln] = ls; }
  }
  __syncthreads();
  if (wid == 0){
    float m1 = mL[0][ln], m2 = mL[1][ln], m3 = mL[2][ln];
    float mstar = fmaxf(fmaxf(m, m1), fmaxf(m2, m3));
    float f0 = __expf(m  - mstar);
    float f1 = __expf(m1 - mstar);
    float f2 = __expf(m2 - mstar);
    float f3 = __expf(m3 - mstar);
    float lstar = f0 * ls + f1 * lsL[0][ln] + f2 * lsL[1][ln] + f3 * lsL[2][ln];
    float inv = 1.0f / lstar;
    float vc0[16], vc1[16];
    #pragma unroll
    for (int r = 0; r < 16; ++r){
      vc0[r] = (f0 * oa0[r] + f1 * oL[0][r][lane] + f2 * oL[1][r][lane]
                + f3 * oL[2][r][lane]) * inv;
      vc1[r] = (f0 * oa1[r] + f1 * oL[0][16 + r][lane] + f2 * oL[1][16 + r][lane]
                + f3 * oL[2][16 + r][lane]) * inv;
    }
    // epilogue: O^T[d][q] -> Oc[b][s=q0+ln][h*64 + d], d = 8g + 4hi + {0..3} (+32 for vc1)
    size_t rowbase = ((size_t)b * SS + q0 + ln) * D_MODEL + h * DK;
    #pragma unroll
    for (int g = 0; g < 4; ++g){
      ushort4 o4;
      o4.x = f2bf(vc0[4*g + 0]); o4.y = f2bf(vc0[4*g + 1]);
      o4.z = f2bf(vc0[4*g + 2]); o4.w = f2bf(vc0[4*g + 3]);
      *(ushort4*)&Oc[rowbase + 8*g + 4*hi] = o4;
    }
    #pragma unroll
    for (int g = 0; g < 4; ++g){
      ushort4 o4;
      o4.x = f2bf(vc1[4*g + 0]); o4.y = f2bf(vc1[4*g + 1]);
      o4.z = f2bf(vc1[4*g + 2]); o4.w = f2bf(vc1[4*g + 3]);
      *(ushort4*)&Oc[rowbase + 32 + 8*g + 4*hi] = o4;
    }
  }
}

extern "C" void kernel_launch(void* const* d_in, const int* in_sizes, int n_in,
                              void* d_out, int out_size, void* d_ws, size_t ws_size,
                              hipStream_t stream){
  const float* q  = (const float*)d_in[0];
  const float* k  = (const float*)d_in[1];
  const float* v  = (const float*)d_in[2];
  // d_in[3]: causal mask (deterministic tril) — hardcoded in attn kernel
  const float* wq = (const float*)d_in[4];
  const float* wk = (const float*)d_in[5];
  const float* wv = (const float*)d_in[6];
  const float* wo = (const float*)d_in[7];
  float* out = (float*)d_out;

  char* ws = (char*)d_ws;
  const size_t MB = 1024 * 1024;
  unsigned short* qb     = (unsigned short*)(ws + 0 * MB);
  unsigned short* kb     = (unsigned short*)(ws + 8 * MB);
  unsigned short* vb     = (unsigned short*)(ws + 16 * MB);
  unsigned short* WqkvT  = (unsigned short*)(ws + 24 * MB);   // 6 MB
  unsigned short* woT    = (unsigned short*)(ws + 30 * MB);
  unsigned short* Qh     = (unsigned short*)(ws + 32 * MB);
  unsigned short* Kh     = (unsigned short*)(ws + 40 * MB);
  unsigned short* VhT    = (unsigned short*)(ws + 48 * MB);
  unsigned short* attnb  = (unsigned short*)(ws + 56 * MB);

  const int n4 = (M_TOT * D_MODEL) / 4;   // per tensor
  dim3 gc(n4 / 256, 3);
  cvt3_bf16<<<gc, 256, 0, stream>>>(q, k, v, qb, kb, vb);

  dim3 tg(16, 16, 4);
  transpose_cvt4<<<tg, 256, 0, stream>>>(wq, wk, wv, wo, WqkvT, woT);

  dim3 gqkv(M_TOT / 128, 3 * D_MODEL / 128);   // (32, 24) = 768 blocks
  gemm_qkv<<<gqkv, 256, 0, stream>>>(qb, kb, vb, WqkvT, Qh, Kh, VhT);

  dim3 ga(BB * NH, SS / 32);                   // (32 bh, 64): qt = 63 - y (LPT)
  attn_kernel<<<ga, 256, 0, stream>>>(Qh, Kh, VhT, attnb);

  dim3 go(M_TOT / 64, D_MODEL / 128);          // (64, 8) = 512 blocks
  gemm_o64<<<go, 256, 0, stream>>>(attnb, woT, out);
}

// Round 7
// 158.373 us; speedup vs baseline: 1.7977x; 1.0405x over previous
//
#include <hip/hip_runtime.h>

#define D_MODEL 1024
#define NH 16
#define DK 64
#define BB 2
#define SS 2048
#define M_TOT (BB*SS)

typedef float f32x4 __attribute__((ext_vector_type(4)));
typedef float f32x16 __attribute__((ext_vector_type(16)));
typedef __bf16 bf16x8 __attribute__((ext_vector_type(8)));
typedef unsigned int u32;

__device__ __forceinline__ unsigned short f2bf(float f){
  unsigned int u = __float_as_uint(f);
  unsigned int r = (u + 0x7fffu + ((u >> 16) & 1u)) >> 16;
  return (unsigned short)r;
}

__device__ __forceinline__ void gload_lds16(const void* g, void* l){
  __builtin_amdgcn_global_load_lds((const __attribute__((address_space(1))) void*)g,
                                   (__attribute__((address_space(3))) void*)l,
                                   16, 0, 0);
}

// exchange 32-lane halves: x = {lo: a.lo, hi: b.lo}, y = {lo: a.hi, hi: b.hi}
__device__ __forceinline__ void swap_half(u32 a, u32 b, int hi, u32& x, u32& y){
#if __has_builtin(__builtin_amdgcn_permlane32_swap)
  typedef unsigned int uint2v __attribute__((ext_vector_type(2)));
  uint2v r = __builtin_amdgcn_permlane32_swap(a, b, false, false);
  x = r.x; y = r.y;
#else
  u32 as = __shfl_xor(a, 32);
  u32 bs = __shfl_xor(b, 32);
  x = hi ? bs : a;
  y = hi ? b  : as;
#endif
}

// ---------------- fp32 -> bf16 convert: q,k,v in one dispatch ----------------
__global__ __launch_bounds__(256) void cvt3_bf16(const float* __restrict__ q,
                                                 const float* __restrict__ k,
                                                 const float* __restrict__ v,
                                                 unsigned short* __restrict__ qb,
                                                 unsigned short* __restrict__ kb,
                                                 unsigned short* __restrict__ vb){
  const int which = blockIdx.y;
  const float* in = (which == 0) ? q : (which == 1) ? k : v;
  unsigned short* out = (which == 0) ? qb : (which == 1) ? kb : vb;
  int i = blockIdx.x * 256 + threadIdx.x;
  float4 f = ((const float4*)in)[i];
  ushort4 o;
  o.x = f2bf(f.x); o.y = f2bf(f.y); o.z = f2bf(f.z); o.w = f2bf(f.w);
  ((ushort4*)out)[i] = o;
}

// ------------- fp32 [K][N] -> bf16 [N][K] transpose-convert, 4 mats -------------
__global__ __launch_bounds__(256) void transpose_cvt4(const float* __restrict__ wq,
                                                      const float* __restrict__ wk,
                                                      const float* __restrict__ wv,
                                                      const float* __restrict__ wo,
                                                      unsigned short* __restrict__ WqkvT,
                                                      unsigned short* __restrict__ woT){
  __shared__ float tile[64][65];
  const int which = blockIdx.z;
  const float* w = (which == 0) ? wq : (which == 1) ? wk : (which == 2) ? wv : wo;
  unsigned short* wt = (which == 3) ? woT : (WqkvT + (size_t)which * 1024 * 1024);
  const int N = D_MODEL;
  const int bx = blockIdx.x * 64;
  const int by = blockIdx.y * 64;
  const int t = threadIdx.x;
  #pragma unroll
  for (int i = 0; i < 16; ++i){
    int idx = t + i * 256;
    int r = idx >> 6, c = idx & 63;
    tile[r][c] = w[(size_t)(by + r) * N + bx + c];
  }
  __syncthreads();
  #pragma unroll
  for (int i = 0; i < 16; ++i){
    int idx = t + i * 256;
    int r = idx >> 6, c = idx & 63;
    wt[(size_t)(bx + r) * N + by + c] = f2bf(tile[c][r]);
  }
}

// ---------------- fused QKV projection GEMM ----------------
__global__ __launch_bounds__(256) void gemm_qkv(const unsigned short* __restrict__ Aq,
                                                const unsigned short* __restrict__ Ak,
                                                const unsigned short* __restrict__ Av,
                                                const unsigned short* __restrict__ WT,
                                                unsigned short* __restrict__ Qh,
                                                unsigned short* __restrict__ Kh,
                                                unsigned short* __restrict__ VhT){
  __shared__ unsigned short Al[2][128 * 32];
  __shared__ unsigned short Bl[2][128 * 32];
  const int tid = threadIdx.x;
  const int wid = tid >> 6, lane = tid & 63;
  const int lr = lane & 15, lg = lane >> 4;
  const int wm = wid >> 1, wn = wid & 1;
  const int bm = blockIdx.x, bn = blockIdx.y;
  const int seg = bn >> 3;
  const unsigned short* A = (seg == 0) ? Aq : (seg == 1) ? Ak : Av;
  const int K = D_MODEL;

  f32x4 acc[4][4];
  #pragma unroll
  for (int i = 0; i < 4; ++i)
    #pragma unroll
    for (int j = 0; j < 4; ++j)
      acc[i][j] = (f32x4){0.f, 0.f, 0.f, 0.f};

  auto stage = [&](int buf, int kt){
    #pragma unroll
    for (int r = 0; r < 2; ++r){
      int vt = tid + r * 256;
      int row = vt >> 2, c8 = (vt & 3) * 8;
      gload_lds16(A  + (size_t)(bm * 128 + row) * K + kt * 32 + c8,
                  &Al[buf][(wid << 9) + r * 2048]);
      gload_lds16(WT + (size_t)(bn * 128 + row) * K + kt * 32 + c8,
                  &Bl[buf][(wid << 9) + r * 2048]);
    }
  };

  stage(0, 0);
  int cur = 0;
  for (int kt = 0; kt < 32; ++kt){
    __syncthreads();
    if (kt + 1 < 32) stage(cur ^ 1, kt + 1);
    bf16x8 af[4], bfr[4];
    #pragma unroll
    for (int i = 0; i < 4; ++i)
      af[i] = *(const bf16x8*)&Al[cur][(wm * 64 + i * 16 + lr) * 32 + lg * 8];
    #pragma unroll
    for (int j = 0; j < 4; ++j)
      bfr[j] = *(const bf16x8*)&Bl[cur][(wn * 64 + j * 16 + lr) * 32 + lg * 8];
    #pragma unroll
    for (int i = 0; i < 4; ++i)
      #pragma unroll
      for (int j = 0; j < 4; ++j)
        acc[i][j] = __builtin_amdgcn_mfma_f32_16x16x32_bf16(af[i], bfr[j], acc[i][j], 0, 0, 0);
    cur ^= 1;
  }

  if (seg < 2){
    unsigned short* O = (seg == 0) ? Qh : Kh;
    #pragma unroll
    for (int i = 0; i < 4; ++i){
      int row0 = bm * 128 + wm * 64 + i * 16 + lg * 4;
      #pragma unroll
      for (int j = 0; j < 4; ++j){
        int colseg = (bn & 7) * 128 + wn * 64 + j * 16 + lr;
        int h = colseg >> 6, dk = colseg & 63;
        #pragma unroll
        for (int p = 0; p < 4; ++p){
          int rowm = row0 + p;
          int b = rowm >> 11, s = rowm & 2047;
          O[((size_t)(b * NH + h) * SS + s) * DK + dk] = f2bf(acc[i][j][p]);
        }
      }
    }
  } else {
    #pragma unroll
    for (int i = 0; i < 4; ++i){
      int row0 = bm * 128 + wm * 64 + i * 16 + lg * 4;
      int b = row0 >> 11, s = row0 & 2047;
      #pragma unroll
      for (int j = 0; j < 4; ++j){
        int colseg = (bn & 7) * 128 + wn * 64 + j * 16 + lr;
        int h = colseg >> 6, dk = colseg & 63;
        ushort4 o4;
        o4.x = f2bf(acc[i][j][0]); o4.y = f2bf(acc[i][j][1]);
        o4.z = f2bf(acc[i][j][2]); o4.w = f2bf(acc[i][j][3]);
        *(ushort4*)&VhT[((size_t)(b * NH + h) * DK + dk) * SS + s] = o4;
      }
    }
  }
}

// ---------------- output projection GEMM (BM=64 for occupancy) ----------------
__global__ __launch_bounds__(256) void gemm_o64(const unsigned short* __restrict__ A,
                                                const unsigned short* __restrict__ Bt,
                                                float* __restrict__ O){
  __shared__ unsigned short Al[2][64 * 32];
  __shared__ unsigned short Bl[2][128 * 32];
  const int tid = threadIdx.x;
  const int wid = tid >> 6, lane = tid & 63;
  const int lr = lane & 15, lg = lane >> 4;
  const int wm = wid >> 1, wn = wid & 1;
  const int bm = blockIdx.x, bn = blockIdx.y;
  const int K = D_MODEL;

  f32x4 acc[2][4];
  #pragma unroll
  for (int i = 0; i < 2; ++i)
    #pragma unroll
    for (int j = 0; j < 4; ++j)
      acc[i][j] = (f32x4){0.f, 0.f, 0.f, 0.f};

  auto stage = [&](int buf, int kt){
    {
      int row = tid >> 2, c8 = (tid & 3) * 8;
      gload_lds16(A + (size_t)(bm * 64 + row) * K + kt * 32 + c8,
                  &Al[buf][wid << 9]);
    }
    #pragma unroll
    for (int r = 0; r < 2; ++r){
      int vt = tid + r * 256;
      int row = vt >> 2, c8 = (vt & 3) * 8;
      gload_lds16(Bt + (size_t)(bn * 128 + row) * K + kt * 32 + c8,
                  &Bl[buf][(wid << 9) + r * 2048]);
    }
  };

  stage(0, 0);
  int cur = 0;
  for (int kt = 0; kt < 32; ++kt){
    __syncthreads();
    if (kt + 1 < 32) stage(cur ^ 1, kt + 1);
    bf16x8 af[2], bfr[4];
    #pragma unroll
    for (int i = 0; i < 2; ++i)
      af[i] = *(const bf16x8*)&Al[cur][(wm * 32 + i * 16 + lr) * 32 + lg * 8];
    #pragma unroll
    for (int j = 0; j < 4; ++j)
      bfr[j] = *(const bf16x8*)&Bl[cur][(wn * 64 + j * 16 + lr) * 32 + lg * 8];
    #pragma unroll
    for (int i = 0; i < 2; ++i)
      #pragma unroll
      for (int j = 0; j < 4; ++j)
        acc[i][j] = __builtin_amdgcn_mfma_f32_16x16x32_bf16(af[i], bfr[j], acc[i][j], 0, 0, 0);
    cur ^= 1;
  }

  #pragma unroll
  for (int i = 0; i < 2; ++i){
    int row0 = bm * 64 + wm * 32 + i * 16 + lg * 4;
    #pragma unroll
    for (int j = 0; j < 4; ++j){
      int col = bn * 128 + wn * 64 + j * 16 + lr;
      #pragma unroll
      for (int p = 0; p < 4; ++p)
        O[(size_t)(row0 + p) * D_MODEL + col] = acc[i][j][p];
    }
  }
}

// ---------------- causal flash attention: shared-LDS K/V staging ----------------
// Block = 2 waves x 32 q-rows (128 thr). Grid (bh=32, 32), qblk = 31-y (LPT).
// Per 64-key step: stage K-tile [64k][64d] + V-tile [64d][64s] coalesced into
// LDS (pre-swizzled source, slot^=row&7; rule #21 both-sides), double-buffered,
// one __syncthreads per step (m97 pattern). Swapped QK^T (S^T via 32x32x16),
// in-register softmax, cvt_pk+half-swap P, PV from LDS V.
__global__ __launch_bounds__(128) void attn_kernel(const unsigned short* __restrict__ Qh,
                                                   const unsigned short* __restrict__ Kh,
                                                   const unsigned short* __restrict__ VhT,
                                                   unsigned short* __restrict__ Oc){
  __shared__ unsigned short Kl[2][64 * 64];   // [buf][k-row][d], 128B rows, 8KB
  __shared__ unsigned short Vl[2][64 * 64];   // [buf][d-row][s], 128B rows, 8KB
  const int bh = blockIdx.x;                  // bh%8 -> XCD stickiness
  const int qblk = 31 - blockIdx.y;           // LPT: longest first
  const int tid = threadIdx.x, wid = tid >> 6, lane = tid & 63;
  const int ln = lane & 31, hi = lane >> 5;
  const int b = bh >> 4, h = bh & 15;
  const size_t kvbase = (size_t)bh * SS * DK;
  const int q0 = qblk * 64 + wid * 32;        // wave's 32 q-rows
  const int Tw = qblk * 2 + wid;              // wave's diagonal 32-key tile
  const int NT = qblk + 1;                    // 64-key steps

  // Q B-fragments (gather once per block)
  const unsigned short* qp = Qh + kvbase + (size_t)(q0 + ln) * DK + hi * 8;
  bf16x8 qbv[4];
  #pragma unroll
  for (int c = 0; c < 4; ++c) qbv[c] = *(const bf16x8*)(qp + c * 16);

  f32x16 oa0 = {0,0,0,0,0,0,0,0,0,0,0,0,0,0,0,0};
  f32x16 oa1 = {0,0,0,0,0,0,0,0,0,0,0,0,0,0,0,0};
  float m = -1e30f, ls = 0.f;

  auto stage = [&](int buf, int t){
    const int k0 = t * 64;
    #pragma unroll
    for (int r = 0; r < 4; ++r){
      const int row = r * 16 + (tid >> 3);           // 0..63
      const int slot = (tid & 7) ^ (row & 7);        // pre-swizzled source slot
      gload_lds16(Kh  + kvbase + (size_t)(k0 + row) * DK + slot * 8,
                  &Kl[buf][r * 1024 + wid * 512]);
      gload_lds16(VhT + kvbase + (size_t)row * SS + k0 + slot * 8,
                  &Vl[buf][r * 1024 + wid * 512]);
    }
  };

  stage(0, 0);
  int cur = 0;
  #pragma unroll 1
  for (int t = 0; t < NT; ++t){
    __syncthreads();                          // drains vmcnt for stage(cur)
    if (t + 1 < NT) stage(cur ^ 1, t + 1);
    const unsigned short* Kb = Kl[cur];
    const unsigned short* Vb = Vl[cur];

    // S^T for sub-tiles a (keys 64t..+31) and b (+32..+63)
    f32x16 sta = {0,0,0,0,0,0,0,0,0,0,0,0,0,0,0,0};
    f32x16 stb = {0,0,0,0,0,0,0,0,0,0,0,0,0,0,0,0};
    #pragma unroll
    for (int c = 0; c < 4; ++c){
      const int po = ((c * 2 + hi) ^ (ln & 7)) * 8;
      bf16x8 kfa = *(const bf16x8*)&Kb[ln * 64 + po];
      bf16x8 kfb = *(const bf16x8*)&Kb[(32 + ln) * 64 + po];
      sta = __builtin_amdgcn_mfma_f32_32x32x16_bf16(kfa, qbv[c], sta, 0, 0, 0);
      stb = __builtin_amdgcn_mfma_f32_32x32x16_bf16(kfb, qbv[c], stb, 0, 0, 0);
    }
    #pragma unroll
    for (int r = 0; r < 16; ++r){ sta[r] *= 0.125f; stb[r] *= 0.125f; }

    // causal: tiles ta=2t, tb=2t+1 vs wave diag Tw (ta>Tw never occurs)
    const int ta = 2 * t, tb = 2 * t + 1;
    if (tb == Tw){
      #pragma unroll
      for (int r = 0; r < 16; ++r){
        int kg = (r & 3) + 8 * (r >> 2) + 4 * hi;
        if (kg > ln) stb[r] = -1e9f;
      }
    } else if (ta == Tw){
      #pragma unroll
      for (int r = 0; r < 16; ++r){
        int kg = (r & 3) + 8 * (r >> 2) + 4 * hi;
        if (kg > ln) sta[r] = -1e9f;
        stb[r] = -1e9f;
      }
    }

    // in-register softmax over 32 values (+ partner half-wave)
    float mx = fmaxf(sta[0], stb[0]);
    #pragma unroll
    for (int r = 1; r < 16; ++r) mx = fmaxf(mx, fmaxf(sta[r], stb[r]));
    mx = fmaxf(mx, __shfl_xor(mx, 32));
    const float mn = fmaxf(m, mx);
    const float fac = __expf(m - mn);
    m = mn;
    float rs = 0.f;
    #pragma unroll
    for (int r = 0; r < 16; ++r){
      float ea = __expf(sta[r] - mn); sta[r] = ea; rs += ea;
      float eb = __expf(stb[r] - mn); stb[r] = eb; rs += eb;
    }
    rs += __shfl_xor(rs, 32);
    ls = ls * fac + rs;
    #pragma unroll
    for (int r = 0; r < 16; ++r){ oa0[r] *= fac; oa1[r] *= fac; }

    // P^T -> bf16 B-fragments (cvt_pk + half-swap), per sub-tile
    u32 ca[8], cb[8];
    #pragma unroll
    for (int i = 0; i < 8; ++i){
      asm("v_cvt_pk_bf16_f32 %0, %1, %2" : "=v"(ca[i]) : "v"(sta[2*i]), "v"(sta[2*i+1]));
      asm("v_cvt_pk_bf16_f32 %0, %1, %2" : "=v"(cb[i]) : "v"(stb[2*i]), "v"(stb[2*i+1]));
    }
    u32 w0[4], w1[4], w2[4], w3[4];
    swap_half(ca[0], ca[2], hi, w0[0], w0[2]);
    swap_half(ca[1], ca[3], hi, w0[1], w0[3]);
    swap_half(ca[4], ca[6], hi, w1[0], w1[2]);
    swap_half(ca[5], ca[7], hi, w1[1], w1[3]);
    swap_half(cb[0], cb[2], hi, w2[0], w2[2]);
    swap_half(cb[1], cb[3], hi, w2[1], w2[3]);
    swap_half(cb[4], cb[6], hi, w3[0], w3[2]);
    swap_half(cb[5], cb[7], hi, w3[1], w3[3]);
    bf16x8 pf[4];
    __builtin_memcpy(&pf[0], w0, 16);
    __builtin_memcpy(&pf[1], w1, 16);
    __builtin_memcpy(&pf[2], w2, 16);
    __builtin_memcpy(&pf[3], w3, 16);

    // O^T += V^T * P^T  (V from LDS, swizzled read)
    #pragma unroll
    for (int ks = 0; ks < 4; ++ks){
      const int po = ((ks * 2 + hi) ^ (ln & 7)) * 8;
      bf16x8 v0 = *(const bf16x8*)&Vb[ln * 64 + po];
      bf16x8 v1 = *(const bf16x8*)&Vb[(32 + ln) * 64 + po];
      oa0 = __builtin_amdgcn_mfma_f32_32x32x16_bf16(v0, pf[ks], oa0, 0, 0, 0);
      oa1 = __builtin_amdgcn_mfma_f32_32x32x16_bf16(v1, pf[ks], oa1, 0, 0, 0);
    }
    cur ^= 1;
  }

  // epilogue: O^T[d][q] -> Oc[b][s=q0+ln][h*64 + d]
  const float inv = 1.0f / ls;
  const size_t rowbase = ((size_t)b * SS + q0 + ln) * D_MODEL + h * DK;
  #pragma unroll
  for (int g = 0; g < 4; ++g){
    ushort4 o4;
    o4.x = f2bf(oa0[4*g + 0] * inv); o4.y = f2bf(oa0[4*g + 1] * inv);
    o4.z = f2bf(oa0[4*g + 2] * inv); o4.w = f2bf(oa0[4*g + 3] * inv);
    *(ushort4*)&Oc[rowbase + 8*g + 4*hi] = o4;
  }
  #pragma unroll
  for (int g = 0; g < 4; ++g){
    ushort4 o4;
    o4.x = f2bf(oa1[4*g + 0] * inv); o4.y = f2bf(oa1[4*g + 1] * inv);
    o4.z = f2bf(oa1[4*g + 2] * inv); o4.w = f2bf(oa1[4*g + 3] * inv);
    *(ushort4*)&Oc[rowbase + 32 + 8*g + 4*hi] = o4;
  }
}

extern "C" void kernel_launch(void* const* d_in, const int* in_sizes, int n_in,
                              void* d_out, int out_size, void* d_ws, size_t ws_size,
                              hipStream_t stream){
  const float* q  = (const float*)d_in[0];
  const float* k  = (const float*)d_in[1];
  const float* v  = (const float*)d_in[2];
  // d_in[3]: causal mask (deterministic tril) — hardcoded in attn kernel
  const float* wq = (const float*)d_in[4];
  const float* wk = (const float*)d_in[5];
  const float* wv = (const float*)d_in[6];
  const float* wo = (const float*)d_in[7];
  float* out = (float*)d_out;

  char* ws = (char*)d_ws;
  const size_t MB = 1024 * 1024;
  unsigned short* qb     = (unsigned short*)(ws + 0 * MB);
  unsigned short* kb     = (unsigned short*)(ws + 8 * MB);
  unsigned short* vb     = (unsigned short*)(ws + 16 * MB);
  unsigned short* WqkvT  = (unsigned short*)(ws + 24 * MB);   // 6 MB
  unsigned short* woT    = (unsigned short*)(ws + 30 * MB);
  unsigned short* Qh     = (unsigned short*)(ws + 32 * MB);
  unsigned short* Kh     = (unsigned short*)(ws + 40 * MB);
  unsigned short* VhT    = (unsigned short*)(ws + 48 * MB);
  unsigned short* attnb  = (unsigned short*)(ws + 56 * MB);

  const int n4 = (M_TOT * D_MODEL) / 4;   // per tensor
  dim3 gc(n4 / 256, 3);
  cvt3_bf16<<<gc, 256, 0, stream>>>(q, k, v, qb, kb, vb);

  dim3 tg(16, 16, 4);
  transpose_cvt4<<<tg, 256, 0, stream>>>(wq, wk, wv, wo, WqkvT, woT);

  dim3 gqkv(M_TOT / 128, 3 * D_MODEL / 128);   // (32, 24) = 768 blocks
  gemm_qkv<<<gqkv, 256, 0, stream>>>(qb, kb, vb, WqkvT, Qh, Kh, VhT);

  dim3 ga(BB * NH, SS / 64);                   // (32 bh, 32): qblk = 31 - y (LPT)
  attn_kernel<<<ga, 128, 0, stream>>>(Qh, Kh, VhT, attnb);

  dim3 go(M_TOT / 64, D_MODEL / 128);          // (64, 8) = 512 blocks
  gemm_o64<<<go, 256, 0, stream>>>(attnb, woT, out);
}

// Round 8
// 137.259 us; speedup vs baseline: 2.0742x; 1.1538x over previous
//
#include <hip/hip_runtime.h>

#define D_MODEL 1024
#define NH 16
#define DK 64
#define BB 2
#define SS 2048
#define M_TOT (BB*SS)

typedef float f32x4 __attribute__((ext_vector_type(4)));
typedef float f32x16 __attribute__((ext_vector_type(16)));
typedef __bf16 bf16x8 __attribute__((ext_vector_type(8)));
typedef unsigned int u32;

// 0.125 (1/sqrt(dk)) * log2(e): folds softmax scaling + base-2 exp into Q
#define QSCALE 0.1803368801f
#define DEFER_THR 11.5416f   // 8 * log2(e): defer-max threshold in log2 domain

__device__ __forceinline__ unsigned short f2bf(float f){
  unsigned int u = __float_as_uint(f);
  unsigned int r = (u + 0x7fffu + ((u >> 16) & 1u)) >> 16;
  return (unsigned short)r;
}

__device__ __forceinline__ void gload_lds16(const void* g, void* l){
  __builtin_amdgcn_global_load_lds((const __attribute__((address_space(1))) void*)g,
                                   (__attribute__((address_space(3))) void*)l,
                                   16, 0, 0);
}

// exchange 32-lane halves: x = {lo: a.lo, hi: b.lo}, y = {lo: a.hi, hi: b.hi}
__device__ __forceinline__ void swap_half(u32 a, u32 b, int hi, u32& x, u32& y){
#if __has_builtin(__builtin_amdgcn_permlane32_swap)
  typedef unsigned int uint2v __attribute__((ext_vector_type(2)));
  uint2v r = __builtin_amdgcn_permlane32_swap(a, b, false, false);
  x = r.x; y = r.y;
#else
  u32 as = __shfl_xor(a, 32);
  u32 bs = __shfl_xor(b, 32);
  x = hi ? bs : a;
  y = hi ? b  : as;
#endif
}

// ---------------- fp32 -> bf16 convert: q,k,v in one dispatch ----------------
__global__ __launch_bounds__(256) void cvt3_bf16(const float* __restrict__ q,
                                                 const float* __restrict__ k,
                                                 const float* __restrict__ v,
                                                 unsigned short* __restrict__ qb,
                                                 unsigned short* __restrict__ kb,
                                                 unsigned short* __restrict__ vb){
  const int which = blockIdx.y;
  const float* in = (which == 0) ? q : (which == 1) ? k : v;
  unsigned short* out = (which == 0) ? qb : (which == 1) ? kb : vb;
  int i = blockIdx.x * 256 + threadIdx.x;
  float4 f = ((const float4*)in)[i];
  ushort4 o;
  o.x = f2bf(f.x); o.y = f2bf(f.y); o.z = f2bf(f.z); o.w = f2bf(f.w);
  ((ushort4*)out)[i] = o;
}

// ------------- fp32 [K][N] -> bf16 [N][K] transpose-convert, 4 mats -------------
__global__ __launch_bounds__(256) void transpose_cvt4(const float* __restrict__ wq,
                                                      const float* __restrict__ wk,
                                                      const float* __restrict__ wv,
                                                      const float* __restrict__ wo,
                                                      unsigned short* __restrict__ WqkvT,
                                                      unsigned short* __restrict__ woT){
  __shared__ float tile[64][65];
  const int which = blockIdx.z;
  const float* w = (which == 0) ? wq : (which == 1) ? wk : (which == 2) ? wv : wo;
  unsigned short* wt = (which == 3) ? woT : (WqkvT + (size_t)which * 1024 * 1024);
  const int N = D_MODEL;
  const int bx = blockIdx.x * 64;
  const int by = blockIdx.y * 64;
  const int t = threadIdx.x;
  #pragma unroll
  for (int i = 0; i < 16; ++i){
    int idx = t + i * 256;
    int r = idx >> 6, c = idx & 63;
    tile[r][c] = w[(size_t)(by + r) * N + bx + c];
  }
  __syncthreads();
  #pragma unroll
  for (int i = 0; i < 16; ++i){
    int idx = t + i * 256;
    int r = idx >> 6, c = idx & 63;
    wt[(size_t)(bx + r) * N + by + c] = f2bf(tile[c][r]);
  }
}

// ---------------- fused QKV projection GEMM ----------------
// seg 0 -> Qh scatter (pre-scaled by QSCALE), seg 1 -> Kh scatter,
// seg 2 -> VhT transposed store.
__global__ __launch_bounds__(256) void gemm_qkv(const unsigned short* __restrict__ Aq,
                                                const unsigned short* __restrict__ Ak,
                                                const unsigned short* __restrict__ Av,
                                                const unsigned short* __restrict__ WT,
                                                unsigned short* __restrict__ Qh,
                                                unsigned short* __restrict__ Kh,
                                                unsigned short* __restrict__ VhT){
  __shared__ unsigned short Al[2][128 * 32];
  __shared__ unsigned short Bl[2][128 * 32];
  const int tid = threadIdx.x;
  const int wid = tid >> 6, lane = tid & 63;
  const int lr = lane & 15, lg = lane >> 4;
  const int wm = wid >> 1, wn = wid & 1;
  const int bm = blockIdx.x, bn = blockIdx.y;
  const int seg = bn >> 3;
  const unsigned short* A = (seg == 0) ? Aq : (seg == 1) ? Ak : Av;
  const int K = D_MODEL;

  f32x4 acc[4][4];
  #pragma unroll
  for (int i = 0; i < 4; ++i)
    #pragma unroll
    for (int j = 0; j < 4; ++j)
      acc[i][j] = (f32x4){0.f, 0.f, 0.f, 0.f};

  auto stage = [&](int buf, int kt){
    #pragma unroll
    for (int r = 0; r < 2; ++r){
      int vt = tid + r * 256;
      int row = vt >> 2, c8 = (vt & 3) * 8;
      gload_lds16(A  + (size_t)(bm * 128 + row) * K + kt * 32 + c8,
                  &Al[buf][(wid << 9) + r * 2048]);
      gload_lds16(WT + (size_t)(bn * 128 + row) * K + kt * 32 + c8,
                  &Bl[buf][(wid << 9) + r * 2048]);
    }
  };

  stage(0, 0);
  int cur = 0;
  for (int kt = 0; kt < 32; ++kt){
    __syncthreads();
    if (kt + 1 < 32) stage(cur ^ 1, kt + 1);
    bf16x8 af[4], bfr[4];
    #pragma unroll
    for (int i = 0; i < 4; ++i)
      af[i] = *(const bf16x8*)&Al[cur][(wm * 64 + i * 16 + lr) * 32 + lg * 8];
    #pragma unroll
    for (int j = 0; j < 4; ++j)
      bfr[j] = *(const bf16x8*)&Bl[cur][(wn * 64 + j * 16 + lr) * 32 + lg * 8];
    #pragma unroll
    for (int i = 0; i < 4; ++i)
      #pragma unroll
      for (int j = 0; j < 4; ++j)
        acc[i][j] = __builtin_amdgcn_mfma_f32_16x16x32_bf16(af[i], bfr[j], acc[i][j], 0, 0, 0);
    cur ^= 1;
  }

  if (seg < 2){
    unsigned short* O = (seg == 0) ? Qh : Kh;
    const float sc = (seg == 0) ? QSCALE : 1.0f;
    #pragma unroll
    for (int i = 0; i < 4; ++i){
      int row0 = bm * 128 + wm * 64 + i * 16 + lg * 4;
      #pragma unroll
      for (int j = 0; j < 4; ++j){
        int colseg = (bn & 7) * 128 + wn * 64 + j * 16 + lr;
        int h = colseg >> 6, dk = colseg & 63;
        #pragma unroll
        for (int p = 0; p < 4; ++p){
          int rowm = row0 + p;
          int b = rowm >> 11, s = rowm & 2047;
          O[((size_t)(b * NH + h) * SS + s) * DK + dk] = f2bf(acc[i][j][p] * sc);
        }
      }
    }
  } else {
    #pragma unroll
    for (int i = 0; i < 4; ++i){
      int row0 = bm * 128 + wm * 64 + i * 16 + lg * 4;
      int b = row0 >> 11, s = row0 & 2047;
      #pragma unroll
      for (int j = 0; j < 4; ++j){
        int colseg = (bn & 7) * 128 + wn * 64 + j * 16 + lr;
        int h = colseg >> 6, dk = colseg & 63;
        ushort4 o4;
        o4.x = f2bf(acc[i][j][0]); o4.y = f2bf(acc[i][j][1]);
        o4.z = f2bf(acc[i][j][2]); o4.w = f2bf(acc[i][j][3]);
        *(ushort4*)&VhT[((size_t)(b * NH + h) * DK + dk) * SS + s] = o4;
      }
    }
  }
}

// ---------------- output projection GEMM (BM=64 for occupancy) ----------------
__global__ __launch_bounds__(256) void gemm_o64(const unsigned short* __restrict__ A,
                                                const unsigned short* __restrict__ Bt,
                                                float* __restrict__ O){
  __shared__ unsigned short Al[2][64 * 32];
  __shared__ unsigned short Bl[2][128 * 32];
  const int tid = threadIdx.x;
  const int wid = tid >> 6, lane = tid & 63;
  const int lr = lane & 15, lg = lane >> 4;
  const int wm = wid >> 1, wn = wid & 1;
  const int bm = blockIdx.x, bn = blockIdx.y;
  const int K = D_MODEL;

  f32x4 acc[2][4];
  #pragma unroll
  for (int i = 0; i < 2; ++i)
    #pragma unroll
    for (int j = 0; j < 4; ++j)
      acc[i][j] = (f32x4){0.f, 0.f, 0.f, 0.f};

  auto stage = [&](int buf, int kt){
    {
      int row = tid >> 2, c8 = (tid & 3) * 8;
      gload_lds16(A + (size_t)(bm * 64 + row) * K + kt * 32 + c8,
                  &Al[buf][wid << 9]);
    }
    #pragma unroll
    for (int r = 0; r < 2; ++r){
      int vt = tid + r * 256;
      int row = vt >> 2, c8 = (vt & 3) * 8;
      gload_lds16(Bt + (size_t)(bn * 128 + row) * K + kt * 32 + c8,
                  &Bl[buf][(wid << 9) + r * 2048]);
    }
  };

  stage(0, 0);
  int cur = 0;
  for (int kt = 0; kt < 32; ++kt){
    __syncthreads();
    if (kt + 1 < 32) stage(cur ^ 1, kt + 1);
    bf16x8 af[2], bfr[4];
    #pragma unroll
    for (int i = 0; i < 2; ++i)
      af[i] = *(const bf16x8*)&Al[cur][(wm * 32 + i * 16 + lr) * 32 + lg * 8];
    #pragma unroll
    for (int j = 0; j < 4; ++j)
      bfr[j] = *(const bf16x8*)&Bl[cur][(wn * 64 + j * 16 + lr) * 32 + lg * 8];
    #pragma unroll
    for (int i = 0; i < 2; ++i)
      #pragma unroll
      for (int j = 0; j < 4; ++j)
        acc[i][j] = __builtin_amdgcn_mfma_f32_16x16x32_bf16(af[i], bfr[j], acc[i][j], 0, 0, 0);
    cur ^= 1;
  }

  #pragma unroll
  for (int i = 0; i < 2; ++i){
    int row0 = bm * 64 + wm * 32 + i * 16 + lg * 4;
    #pragma unroll
    for (int j = 0; j < 4; ++j){
      int col = bn * 128 + wn * 64 + j * 16 + lr;
      #pragma unroll
      for (int p = 0; p < 4; ++p)
        O[(size_t)(row0 + p) * D_MODEL + col] = acc[i][j][p];
    }
  }
}

// ---------------- causal flash attention: shared-LDS K/V, log2-domain softmax ----------------
// Round-7 structure + VALU diet: Q pre-scaled by 0.125*log2e (scores arrive in
// log2 domain, P = native v_exp_f32), tree max/sum (depth 5), defer-max (T13,
// skip rescale unless any lane's max grew > 8 nats), setprio around MFMA (T5).
__global__ __launch_bounds__(128) void attn_kernel(const unsigned short* __restrict__ Qh,
                                                   const unsigned short* __restrict__ Kh,
                                                   const unsigned short* __restrict__ VhT,
                                                   unsigned short* __restrict__ Oc){
  __shared__ unsigned short Kl[2][64 * 64];
  __shared__ unsigned short Vl[2][64 * 64];
  const int bh = blockIdx.x;                  // bh%8 -> XCD stickiness
  const int qblk = 31 - blockIdx.y;           // LPT: longest first
  const int tid = threadIdx.x, wid = tid >> 6, lane = tid & 63;
  const int ln = lane & 31, hi = lane >> 5;
  const int b = bh >> 4, h = bh & 15;
  const size_t kvbase = (size_t)bh * SS * DK;
  const int q0 = qblk * 64 + wid * 32;
  const int Tw = qblk * 2 + wid;              // wave's diagonal 32-key tile
  const int NT = qblk + 1;                    // 64-key steps

  const unsigned short* qp = Qh + kvbase + (size_t)(q0 + ln) * DK + hi * 8;
  bf16x8 qbv[4];
  #pragma unroll
  for (int c = 0; c < 4; ++c) qbv[c] = *(const bf16x8*)(qp + c * 16);

  f32x16 oa0 = {0,0,0,0,0,0,0,0,0,0,0,0,0,0,0,0};
  f32x16 oa1 = {0,0,0,0,0,0,0,0,0,0,0,0,0,0,0,0};
  float m = -1e30f, ls = 0.f;

  auto stage = [&](int buf, int t){
    const int k0 = t * 64;
    #pragma unroll
    for (int r = 0; r < 4; ++r){
      const int row = r * 16 + (tid >> 3);
      const int slot = (tid & 7) ^ (row & 7);
      gload_lds16(Kh  + kvbase + (size_t)(k0 + row) * DK + slot * 8,
                  &Kl[buf][r * 1024 + wid * 512]);
      gload_lds16(VhT + kvbase + (size_t)row * SS + k0 + slot * 8,
                  &Vl[buf][r * 1024 + wid * 512]);
    }
  };

  stage(0, 0);
  int cur = 0;
  #pragma unroll 1
  for (int t = 0; t < NT; ++t){
    __syncthreads();
    if (t + 1 < NT) stage(cur ^ 1, t + 1);
    const unsigned short* Kb = Kl[cur];
    const unsigned short* Vb = Vl[cur];

    // S^T (log2 domain, pre-scaled Q) for key sub-tiles a/b
    f32x16 sta = {0,0,0,0,0,0,0,0,0,0,0,0,0,0,0,0};
    f32x16 stb = {0,0,0,0,0,0,0,0,0,0,0,0,0,0,0,0};
    __builtin_amdgcn_s_setprio(1);
    #pragma unroll
    for (int c = 0; c < 4; ++c){
      const int po = ((c * 2 + hi) ^ (ln & 7)) * 8;
      bf16x8 kfa = *(const bf16x8*)&Kb[ln * 64 + po];
      bf16x8 kfb = *(const bf16x8*)&Kb[(32 + ln) * 64 + po];
      sta = __builtin_amdgcn_mfma_f32_32x32x16_bf16(kfa, qbv[c], sta, 0, 0, 0);
      stb = __builtin_amdgcn_mfma_f32_32x32x16_bf16(kfb, qbv[c], stb, 0, 0, 0);
    }
    __builtin_amdgcn_s_setprio(0);

    // causal mask: tiles ta=2t, tb=2t+1 vs wave diag Tw
    const int ta = 2 * t, tb = 2 * t + 1;
    if (tb == Tw){
      #pragma unroll
      for (int r = 0; r < 16; ++r){
        int kg = (r & 3) + 8 * (r >> 2) + 4 * hi;
        if (kg > ln) stb[r] = -1e30f;
      }
    } else if (ta == Tw){
      #pragma unroll
      for (int r = 0; r < 16; ++r){
        int kg = (r & 3) + 8 * (r >> 2) + 4 * hi;
        if (kg > ln) sta[r] = -1e30f;
        stb[r] = -1e30f;
      }
    }

    // tree max (depth 5)
    float tm[8];
    #pragma unroll
    for (int i = 0; i < 8; ++i)
      tm[i] = fmaxf(fmaxf(sta[2*i], sta[2*i+1]), fmaxf(stb[2*i], stb[2*i+1]));
    float mx = fmaxf(fmaxf(fmaxf(tm[0], tm[1]), fmaxf(tm[2], tm[3])),
                     fmaxf(fmaxf(tm[4], tm[5]), fmaxf(tm[6], tm[7])));
    mx = fmaxf(mx, __shfl_xor(mx, 32));

    // defer-max: rescale only when some lane's max grew past threshold
    if (__any(mx > m + DEFER_THR)){
      const float mn = fmaxf(m, mx);
      const float fac = __builtin_amdgcn_exp2f(m - mn);
      m = mn;
      ls *= fac;
      #pragma unroll
      for (int r = 0; r < 16; ++r){ oa0[r] *= fac; oa1[r] *= fac; }
    }

    // P = exp2(st - m), tree sum
    #pragma unroll
    for (int r = 0; r < 16; ++r){
      sta[r] = __builtin_amdgcn_exp2f(sta[r] - m);
      stb[r] = __builtin_amdgcn_exp2f(stb[r] - m);
    }
    float sm[8];
    #pragma unroll
    for (int i = 0; i < 8; ++i)
      sm[i] = (sta[2*i] + sta[2*i+1]) + (stb[2*i] + stb[2*i+1]);
    float rs = ((sm[0] + sm[1]) + (sm[2] + sm[3])) + ((sm[4] + sm[5]) + (sm[6] + sm[7]));
    rs += __shfl_xor(rs, 32);
    ls += rs;

    // P^T -> bf16 B-fragments (cvt_pk + half-swap)
    u32 ca[8], cb[8];
    #pragma unroll
    for (int i = 0; i < 8; ++i){
      asm("v_cvt_pk_bf16_f32 %0, %1, %2" : "=v"(ca[i]) : "v"(sta[2*i]), "v"(sta[2*i+1]));
      asm("v_cvt_pk_bf16_f32 %0, %1, %2" : "=v"(cb[i]) : "v"(stb[2*i]), "v"(stb[2*i+1]));
    }
    u32 w0[4], w1[4], w2[4], w3[4];
    swap_half(ca[0], ca[2], hi, w0[0], w0[2]);
    swap_half(ca[1], ca[3], hi, w0[1], w0[3]);
    swap_half(ca[4], ca[6], hi, w1[0], w1[2]);
    swap_half(ca[5], ca[7], hi, w1[1], w1[3]);
    swap_half(cb[0], cb[2], hi, w2[0], w2[2]);
    swap_half(cb[1], cb[3], hi, w2[1], w2[3]);
    swap_half(cb[4], cb[6], hi, w3[0], w3[2]);
    swap_half(cb[5], cb[7], hi, w3[1], w3[3]);
    bf16x8 pf[4];
    __builtin_memcpy(&pf[0], w0, 16);
    __builtin_memcpy(&pf[1], w1, 16);
    __builtin_memcpy(&pf[2], w2, 16);
    __builtin_memcpy(&pf[3], w3, 16);

    // O^T += V^T * P^T
    __builtin_amdgcn_s_setprio(1);
    #pragma unroll
    for (int ks = 0; ks < 4; ++ks){
      const int po = ((ks * 2 + hi) ^ (ln & 7)) * 8;
      bf16x8 v0 = *(const bf16x8*)&Vb[ln * 64 + po];
      bf16x8 v1 = *(const bf16x8*)&Vb[(32 + ln) * 64 + po];
      oa0 = __builtin_amdgcn_mfma_f32_32x32x16_bf16(v0, pf[ks], oa0, 0, 0, 0);
      oa1 = __builtin_amdgcn_mfma_f32_32x32x16_bf16(v1, pf[ks], oa1, 0, 0, 0);
    }
    __builtin_amdgcn_s_setprio(0);
    cur ^= 1;
  }

  // epilogue
  const float inv = 1.0f / ls;
  const size_t rowbase = ((size_t)b * SS + q0 + ln) * D_MODEL + h * DK;
  #pragma unroll
  for (int g = 0; g < 4; ++g){
    ushort4 o4;
    o4.x = f2bf(oa0[4*g + 0] * inv); o4.y = f2bf(oa0[4*g + 1] * inv);
    o4.z = f2bf(oa0[4*g + 2] * inv); o4.w = f2bf(oa0[4*g + 3] * inv);
    *(ushort4*)&Oc[rowbase + 8*g + 4*hi] = o4;
  }
  #pragma unroll
  for (int g = 0; g < 4; ++g){
    ushort4 o4;
    o4.x = f2bf(oa1[4*g + 0] * inv); o4.y = f2bf(oa1[4*g + 1] * inv);
    o4.z = f2bf(oa1[4*g + 2] * inv); o4.w = f2bf(oa1[4*g + 3] * inv);
    *(ushort4*)&Oc[rowbase + 32 + 8*g + 4*hi] = o4;
  }
}

extern "C" void kernel_launch(void* const* d_in, const int* in_sizes, int n_in,
                              void* d_out, int out_size, void* d_ws, size_t ws_size,
                              hipStream_t stream){
  const float* q  = (const float*)d_in[0];
  const float* k  = (const float*)d_in[1];
  const float* v  = (const float*)d_in[2];
  // d_in[3]: causal mask (deterministic tril) — hardcoded in attn kernel
  const float* wq = (const float*)d_in[4];
  const float* wk = (const float*)d_in[5];
  const float* wv = (const float*)d_in[6];
  const float* wo = (const float*)d_in[7];
  float* out = (float*)d_out;

  char* ws = (char*)d_ws;
  const size_t MB = 1024 * 1024;
  unsigned short* qb     = (unsigned short*)(ws + 0 * MB);
  unsigned short* kb     = (unsigned short*)(ws + 8 * MB);
  unsigned short* vb     = (unsigned short*)(ws + 16 * MB);
  unsigned short* WqkvT  = (unsigned short*)(ws + 24 * MB);   // 6 MB
  unsigned short* woT    = (unsigned short*)(ws + 30 * MB);
  unsigned short* Qh     = (unsigned short*)(ws + 32 * MB);
  unsigned short* Kh     = (unsigned short*)(ws + 40 * MB);
  unsigned short* VhT    = (unsigned short*)(ws + 48 * MB);
  unsigned short* attnb  = (unsigned short*)(ws + 56 * MB);

  const int n4 = (M_TOT * D_MODEL) / 4;   // per tensor
  dim3 gc(n4 / 256, 3);
  cvt3_bf16<<<gc, 256, 0, stream>>>(q, k, v, qb, kb, vb);

  dim3 tg(16, 16, 4);
  transpose_cvt4<<<tg, 256, 0, stream>>>(wq, wk, wv, wo, WqkvT, woT);

  dim3 gqkv(M_TOT / 128, 3 * D_MODEL / 128);   // (32, 24) = 768 blocks
  gemm_qkv<<<gqkv, 256, 0, stream>>>(qb, kb, vb, WqkvT, Qh, Kh, VhT);

  dim3 ga(BB * NH, SS / 64);                   // (32 bh, 32): qblk = 31 - y (LPT)
  attn_kernel<<<ga, 128, 0, stream>>>(Qh, Kh, VhT, attnb);

  dim3 go(M_TOT / 64, D_MODEL / 128);          // (64, 8) = 512 blocks
  gemm_o64<<<go, 256, 0, stream>>>(attnb, woT, out);
}

// Round 9
// 121.501 us; speedup vs baseline: 2.3432x; 1.1297x over previous
//
#include <hip/hip_runtime.h>

#define D_MODEL 1024
#define NH 16
#define DK 64
#define BB 2
#define SS 2048
#define M_TOT (BB*SS)

typedef float f32x4 __attribute__((ext_vector_type(4)));
typedef float f32x16 __attribute__((ext_vector_type(16)));
typedef __bf16 bf16x8 __attribute__((ext_vector_type(8)));
typedef unsigned int u32;

// 0.125 (1/sqrt(dk)) * log2(e): folds softmax scaling + base-2 exp into Q
#define QSCALE 0.1803368801f
#define DEFER_THR 11.5416f   // 8 * log2(e)

__device__ __forceinline__ unsigned short f2bf(float f){
  unsigned int u = __float_as_uint(f);
  unsigned int r = (u + 0x7fffu + ((u >> 16) & 1u)) >> 16;
  return (unsigned short)r;
}

__device__ __forceinline__ void gload_lds16(const void* g, void* l){
  __builtin_amdgcn_global_load_lds((const __attribute__((address_space(1))) void*)g,
                                   (__attribute__((address_space(3))) void*)l,
                                   16, 0, 0);
}

// exchange 32-lane halves: x = {lo: a.lo, hi: b.lo}, y = {lo: a.hi, hi: b.hi}
__device__ __forceinline__ void swap_half(u32 a, u32 b, int hi, u32& x, u32& y){
#if __has_builtin(__builtin_amdgcn_permlane32_swap)
  typedef unsigned int uint2v __attribute__((ext_vector_type(2)));
  uint2v r = __builtin_amdgcn_permlane32_swap(a, b, false, false);
  x = r.x; y = r.y;
#else
  u32 as = __shfl_xor(a, 32);
  u32 bs = __shfl_xor(b, 32);
  x = hi ? bs : a;
  y = hi ? b  : as;
#endif
}

// ---------------- fp32 -> bf16 convert: q,k,v in one dispatch ----------------
__global__ __launch_bounds__(256) void cvt3_bf16(const float* __restrict__ q,
                                                 const float* __restrict__ k,
                                                 const float* __restrict__ v,
                                                 unsigned short* __restrict__ qb,
                                                 unsigned short* __restrict__ kb,
                                                 unsigned short* __restrict__ vb){
  const int which = blockIdx.y;
  const float* in = (which == 0) ? q : (which == 1) ? k : v;
  unsigned short* out = (which == 0) ? qb : (which == 1) ? kb : vb;
  int i = blockIdx.x * 256 + threadIdx.x;
  float4 f = ((const float4*)in)[i];
  ushort4 o;
  o.x = f2bf(f.x); o.y = f2bf(f.y); o.z = f2bf(f.z); o.w = f2bf(f.w);
  ((ushort4*)out)[i] = o;
}

// ------------- fp32 [K][N] -> bf16 [N][K] transpose-convert, 4 mats -------------
__global__ __launch_bounds__(256) void transpose_cvt4(const float* __restrict__ wq,
                                                      const float* __restrict__ wk,
                                                      const float* __restrict__ wv,
                                                      const float* __restrict__ wo,
                                                      unsigned short* __restrict__ WqkvT,
                                                      unsigned short* __restrict__ woT){
  __shared__ float tile[64][65];
  const int which = blockIdx.z;
  const float* w = (which == 0) ? wq : (which == 1) ? wk : (which == 2) ? wv : wo;
  unsigned short* wt = (which == 3) ? woT : (WqkvT + (size_t)which * 1024 * 1024);
  const int N = D_MODEL;
  const int bx = blockIdx.x * 64;
  const int by = blockIdx.y * 64;
  const int t = threadIdx.x;
  #pragma unroll
  for (int i = 0; i < 16; ++i){
    int idx = t + i * 256;
    int r = idx >> 6, c = idx & 63;
    tile[r][c] = w[(size_t)(by + r) * N + bx + c];
  }
  __syncthreads();
  #pragma unroll
  for (int i = 0; i < 16; ++i){
    int idx = t + i * 256;
    int r = idx >> 6, c = idx & 63;
    wt[(size_t)(bx + r) * N + by + c] = f2bf(tile[c][r]);
  }
}

// ---------------- fused QKV projection GEMM ----------------
// seg 0 -> Qh scatter (pre-scaled by QSCALE), seg 1 -> Kh scatter,
// seg 2 -> VhT transposed store.
__global__ __launch_bounds__(256) void gemm_qkv(const unsigned short* __restrict__ Aq,
                                                const unsigned short* __restrict__ Ak,
                                                const unsigned short* __restrict__ Av,
                                                const unsigned short* __restrict__ WT,
                                                unsigned short* __restrict__ Qh,
                                                unsigned short* __restrict__ Kh,
                                                unsigned short* __restrict__ VhT){
  __shared__ unsigned short Al[2][128 * 32];
  __shared__ unsigned short Bl[2][128 * 32];
  const int tid = threadIdx.x;
  const int wid = tid >> 6, lane = tid & 63;
  const int lr = lane & 15, lg = lane >> 4;
  const int wm = wid >> 1, wn = wid & 1;
  const int bm = blockIdx.x, bn = blockIdx.y;
  const int seg = bn >> 3;
  const unsigned short* A = (seg == 0) ? Aq : (seg == 1) ? Ak : Av;
  const int K = D_MODEL;

  f32x4 acc[4][4];
  #pragma unroll
  for (int i = 0; i < 4; ++i)
    #pragma unroll
    for (int j = 0; j < 4; ++j)
      acc[i][j] = (f32x4){0.f, 0.f, 0.f, 0.f};

  auto stage = [&](int buf, int kt){
    #pragma unroll
    for (int r = 0; r < 2; ++r){
      int vt = tid + r * 256;
      int row = vt >> 2, c8 = (vt & 3) * 8;
      gload_lds16(A  + (size_t)(bm * 128 + row) * K + kt * 32 + c8,
                  &Al[buf][(wid << 9) + r * 2048]);
      gload_lds16(WT + (size_t)(bn * 128 + row) * K + kt * 32 + c8,
                  &Bl[buf][(wid << 9) + r * 2048]);
    }
  };

  stage(0, 0);
  int cur = 0;
  for (int kt = 0; kt < 32; ++kt){
    __syncthreads();
    if (kt + 1 < 32) stage(cur ^ 1, kt + 1);
    bf16x8 af[4], bfr[4];
    #pragma unroll
    for (int i = 0; i < 4; ++i)
      af[i] = *(const bf16x8*)&Al[cur][(wm * 64 + i * 16 + lr) * 32 + lg * 8];
    #pragma unroll
    for (int j = 0; j < 4; ++j)
      bfr[j] = *(const bf16x8*)&Bl[cur][(wn * 64 + j * 16 + lr) * 32 + lg * 8];
    #pragma unroll
    for (int i = 0; i < 4; ++i)
      #pragma unroll
      for (int j = 0; j < 4; ++j)
        acc[i][j] = __builtin_amdgcn_mfma_f32_16x16x32_bf16(af[i], bfr[j], acc[i][j], 0, 0, 0);
    cur ^= 1;
  }

  if (seg < 2){
    unsigned short* O = (seg == 0) ? Qh : Kh;
    const float sc = (seg == 0) ? QSCALE : 1.0f;
    #pragma unroll
    for (int i = 0; i < 4; ++i){
      int row0 = bm * 128 + wm * 64 + i * 16 + lg * 4;
      #pragma unroll
      for (int j = 0; j < 4; ++j){
        int colseg = (bn & 7) * 128 + wn * 64 + j * 16 + lr;
        int h = colseg >> 6, dk = colseg & 63;
        #pragma unroll
        for (int p = 0; p < 4; ++p){
          int rowm = row0 + p;
          int b = rowm >> 11, s = rowm & 2047;
          O[((size_t)(b * NH + h) * SS + s) * DK + dk] = f2bf(acc[i][j][p] * sc);
        }
      }
    }
  } else {
    #pragma unroll
    for (int i = 0; i < 4; ++i){
      int row0 = bm * 128 + wm * 64 + i * 16 + lg * 4;
      int b = row0 >> 11, s = row0 & 2047;
      #pragma unroll
      for (int j = 0; j < 4; ++j){
        int colseg = (bn & 7) * 128 + wn * 64 + j * 16 + lr;
        int h = colseg >> 6, dk = colseg & 63;
        ushort4 o4;
        o4.x = f2bf(acc[i][j][0]); o4.y = f2bf(acc[i][j][1]);
        o4.z = f2bf(acc[i][j][2]); o4.w = f2bf(acc[i][j][3]);
        *(ushort4*)&VhT[((size_t)(b * NH + h) * DK + dk) * SS + s] = o4;
      }
    }
  }
}

// ---------------- output projection GEMM (BM=64 for occupancy) ----------------
__global__ __launch_bounds__(256) void gemm_o64(const unsigned short* __restrict__ A,
                                                const unsigned short* __restrict__ Bt,
                                                float* __restrict__ O){
  __shared__ unsigned short Al[2][64 * 32];
  __shared__ unsigned short Bl[2][128 * 32];
  const int tid = threadIdx.x;
  const int wid = tid >> 6, lane = tid & 63;
  const int lr = lane & 15, lg = lane >> 4;
  const int wm = wid >> 1, wn = wid & 1;
  const int bm = blockIdx.x, bn = blockIdx.y;
  const int K = D_MODEL;

  f32x4 acc[2][4];
  #pragma unroll
  for (int i = 0; i < 2; ++i)
    #pragma unroll
    for (int j = 0; j < 4; ++j)
      acc[i][j] = (f32x4){0.f, 0.f, 0.f, 0.f};

  auto stage = [&](int buf, int kt){
    {
      int row = tid >> 2, c8 = (tid & 3) * 8;
      gload_lds16(A + (size_t)(bm * 64 + row) * K + kt * 32 + c8,
                  &Al[buf][wid << 9]);
    }
    #pragma unroll
    for (int r = 0; r < 2; ++r){
      int vt = tid + r * 256;
      int row = vt >> 2, c8 = (vt & 3) * 8;
      gload_lds16(Bt + (size_t)(bn * 128 + row) * K + kt * 32 + c8,
                  &Bl[buf][(wid << 9) + r * 2048]);
    }
  };

  stage(0, 0);
  int cur = 0;
  for (int kt = 0; kt < 32; ++kt){
    __syncthreads();
    if (kt + 1 < 32) stage(cur ^ 1, kt + 1);
    bf16x8 af[2], bfr[4];
    #pragma unroll
    for (int i = 0; i < 2; ++i)
      af[i] = *(const bf16x8*)&Al[cur][(wm * 32 + i * 16 + lr) * 32 + lg * 8];
    #pragma unroll
    for (int j = 0; j < 4; ++j)
      bfr[j] = *(const bf16x8*)&Bl[cur][(wn * 64 + j * 16 + lr) * 32 + lg * 8];
    #pragma unroll
    for (int i = 0; i < 2; ++i)
      #pragma unroll
      for (int j = 0; j < 4; ++j)
        acc[i][j] = __builtin_amdgcn_mfma_f32_16x16x32_bf16(af[i], bfr[j], acc[i][j], 0, 0, 0);
    cur ^= 1;
  }

  #pragma unroll
  for (int i = 0; i < 2; ++i){
    int row0 = bm * 64 + wm * 32 + i * 16 + lg * 4;
    #pragma unroll
    for (int j = 0; j < 4; ++j){
      int col = bn * 128 + wn * 64 + j * 16 + lr;
      #pragma unroll
      for (int p = 0; p < 4; ++p)
        O[(size_t)(row0 + p) * D_MODEL + col] = acc[i][j][p];
    }
  }
}

// ---------------- causal flash attention: 4-wave split-K, all-resident ----------------
// Block = 4 waves, 64 q-rows. Wave = (q-half wid&1, K-parity wid>>1).
// Pair 0 computes even 64-key tiles, pair 1 odd tiles -> critical path halves.
// Single-buffered pair staging (KA,VA,KB,VB = 32 KB), two barriers/round.
// 1024 blocks x 4 waves: 4 blocks/CU -> ALL blocks resident (no dispatch tail).
// End: 2-way in-LDS combine (exp2 domain). Compute body = round-8 proven.
__global__ __launch_bounds__(256) void attn_kernel(const unsigned short* __restrict__ Qh,
                                                   const unsigned short* __restrict__ Kh,
                                                   const unsigned short* __restrict__ VhT,
                                                   unsigned short* __restrict__ Oc){
  __shared__ unsigned short SL[4][4096];      // KA | VA | KB | VB, 8 KB each
  const int bh = blockIdx.x;                  // bh%8 -> XCD stickiness
  const int qblk = 31 - blockIdx.y;           // LPT (harmless when all resident)
  const int tid = threadIdx.x, wid = tid >> 6, lane = tid & 63;
  const int ln = lane & 31, hi = lane >> 5;
  const int qh = wid & 1, pp = wid >> 1;      // q-half, K-parity
  const int b = bh >> 4, h = bh & 15;
  const size_t kvbase = (size_t)bh * SS * DK;
  const int q0 = qblk * 64 + qh * 32;
  const int Tw = 2 * qblk + qh;               // wave's diagonal 32-key tile
  const int R = (qblk + 2) >> 1;              // rounds (pairs of 64-key tiles)

  const unsigned short* qp = Qh + kvbase + (size_t)(q0 + ln) * DK + hi * 8;
  bf16x8 qbv[4];
  #pragma unroll
  for (int c = 0; c < 4; ++c) qbv[c] = *(const bf16x8*)(qp + c * 16);

  f32x16 oa0 = {0,0,0,0,0,0,0,0,0,0,0,0,0,0,0,0};
  f32x16 oa1 = {0,0,0,0,0,0,0,0,0,0,0,0,0,0,0,0};
  float m = -1e30f, ls = 0.f;

  #pragma unroll 1
  for (int r = 0; r < R; ++r){
    // ---- stage tile pair (tA=2r always; tB=2r+1 if <= qblk) ----
    {
      const int k0A = (2 * r) * 64;
      const int k0B = k0A + 64;
      const bool haveB = (2 * r + 1) <= qblk;
      #pragma unroll
      for (int i = 0; i < 2; ++i){
        const int c = i * 256 + tid;
        const int row = c >> 3;
        const int slot = (c & 7) ^ (row & 7);
        const int ldso = (i * 256 + wid * 64) * 8;   // shorts, wave-uniform
        gload_lds16(Kh  + kvbase + (size_t)(k0A + row) * DK + slot * 8, &SL[0][ldso]);
        gload_lds16(VhT + kvbase + (size_t)row * SS + k0A + slot * 8,   &SL[1][ldso]);
        if (haveB){
          gload_lds16(Kh  + kvbase + (size_t)(k0B + row) * DK + slot * 8, &SL[2][ldso]);
          gload_lds16(VhT + kvbase + (size_t)row * SS + k0B + slot * 8,   &SL[3][ldso]);
        }
      }
    }
    __syncthreads();                          // staging complete

    const int t = 2 * r + pp;
    if (t <= qblk){
      const unsigned short* Kb = SL[pp * 2];
      const unsigned short* Vb = SL[pp * 2 + 1];

      // S^T (log2 domain) for key sub-tiles a/b of this 64-key tile
      f32x16 sta = {0,0,0,0,0,0,0,0,0,0,0,0,0,0,0,0};
      f32x16 stb = {0,0,0,0,0,0,0,0,0,0,0,0,0,0,0,0};
      __builtin_amdgcn_s_setprio(1);
      #pragma unroll
      for (int c = 0; c < 4; ++c){
        const int po = ((c * 2 + hi) ^ (ln & 7)) * 8;
        bf16x8 kfa = *(const bf16x8*)&Kb[ln * 64 + po];
        bf16x8 kfb = *(const bf16x8*)&Kb[(32 + ln) * 64 + po];
        sta = __builtin_amdgcn_mfma_f32_32x32x16_bf16(kfa, qbv[c], sta, 0, 0, 0);
        stb = __builtin_amdgcn_mfma_f32_32x32x16_bf16(kfb, qbv[c], stb, 0, 0, 0);
      }
      __builtin_amdgcn_s_setprio(0);

      // causal mask: 32-key tiles ta=2t, tb=2t+1 vs wave diag Tw
      const int ta = 2 * t, tb = 2 * t + 1;
      if (tb == Tw){
        #pragma unroll
        for (int rr = 0; rr < 16; ++rr){
          int kg = (rr & 3) + 8 * (rr >> 2) + 4 * hi;
          if (kg > ln) stb[rr] = -1e30f;
        }
      } else if (ta == Tw){
        #pragma unroll
        for (int rr = 0; rr < 16; ++rr){
          int kg = (rr & 3) + 8 * (rr >> 2) + 4 * hi;
          if (kg > ln) sta[rr] = -1e30f;
          stb[rr] = -1e30f;
        }
      }

      // tree max
      float tm[8];
      #pragma unroll
      for (int i = 0; i < 8; ++i)
        tm[i] = fmaxf(fmaxf(sta[2*i], sta[2*i+1]), fmaxf(stb[2*i], stb[2*i+1]));
      float mx = fmaxf(fmaxf(fmaxf(tm[0], tm[1]), fmaxf(tm[2], tm[3])),
                       fmaxf(fmaxf(tm[4], tm[5]), fmaxf(tm[6], tm[7])));
      mx = fmaxf(mx, __shfl_xor(mx, 32));

      // defer-max rescale
      if (__any(mx > m + DEFER_THR)){
        const float mn = fmaxf(m, mx);
        const float fac = __builtin_amdgcn_exp2f(m - mn);
        m = mn;
        ls *= fac;
        #pragma unroll
        for (int rr = 0; rr < 16; ++rr){ oa0[rr] *= fac; oa1[rr] *= fac; }
      }

      // P = exp2(st - m), tree sum
      #pragma unroll
      for (int rr = 0; rr < 16; ++rr){
        sta[rr] = __builtin_amdgcn_exp2f(sta[rr] - m);
        stb[rr] = __builtin_amdgcn_exp2f(stb[rr] - m);
      }
      float sm[8];
      #pragma unroll
      for (int i = 0; i < 8; ++i)
        sm[i] = (sta[2*i] + sta[2*i+1]) + (stb[2*i] + stb[2*i+1]);
      float rsum = ((sm[0] + sm[1]) + (sm[2] + sm[3])) + ((sm[4] + sm[5]) + (sm[6] + sm[7]));
      rsum += __shfl_xor(rsum, 32);
      ls += rsum;

      // P^T -> bf16 B-fragments
      u32 ca[8], cb[8];
      #pragma unroll
      for (int i = 0; i < 8; ++i){
        asm("v_cvt_pk_bf16_f32 %0, %1, %2" : "=v"(ca[i]) : "v"(sta[2*i]), "v"(sta[2*i+1]));
        asm("v_cvt_pk_bf16_f32 %0, %1, %2" : "=v"(cb[i]) : "v"(stb[2*i]), "v"(stb[2*i+1]));
      }
      u32 w0[4], w1[4], w2[4], w3[4];
      swap_half(ca[0], ca[2], hi, w0[0], w0[2]);
      swap_half(ca[1], ca[3], hi, w0[1], w0[3]);
      swap_half(ca[4], ca[6], hi, w1[0], w1[2]);
      swap_half(ca[5], ca[7], hi, w1[1], w1[3]);
      swap_half(cb[0], cb[2], hi, w2[0], w2[2]);
      swap_half(cb[1], cb[3], hi, w2[1], w2[3]);
      swap_half(cb[4], cb[6], hi, w3[0], w3[2]);
      swap_half(cb[5], cb[7], hi, w3[1], w3[3]);
      bf16x8 pf[4];
      __builtin_memcpy(&pf[0], w0, 16);
      __builtin_memcpy(&pf[1], w1, 16);
      __builtin_memcpy(&pf[2], w2, 16);
      __builtin_memcpy(&pf[3], w3, 16);

      // O^T += V^T * P^T
      __builtin_amdgcn_s_setprio(1);
      #pragma unroll
      for (int ks = 0; ks < 4; ++ks){
        const int po = ((ks * 2 + hi) ^ (ln & 7)) * 8;
        bf16x8 v0 = *(const bf16x8*)&Vb[ln * 64 + po];
        bf16x8 v1 = *(const bf16x8*)&Vb[(32 + ln) * 64 + po];
        oa0 = __builtin_amdgcn_mfma_f32_32x32x16_bf16(v0, pf[ks], oa0, 0, 0, 0);
        oa1 = __builtin_amdgcn_mfma_f32_32x32x16_bf16(v1, pf[ks], oa1, 0, 0, 0);
      }
      __builtin_amdgcn_s_setprio(0);
    }
    __syncthreads();                          // all reads done before next stage
  }

  // ---- 2-way split-K combine (exp2 domain) ----
  float* oL  = (float*)&SL[0][0];             // [2][32][64] f32 = 16 KB
  float* mLs = (float*)&SL[2][0];             // mL[2][32] | lsL[2][32]
  if (wid >= 2){
    const int w = wid - 2;
    #pragma unroll
    for (int rr = 0; rr < 16; ++rr){
      oL[(w * 32 + rr) * 64 + lane]      = oa0[rr];
      oL[(w * 32 + 16 + rr) * 64 + lane] = oa1[rr];
    }
    if (hi == 0){ mLs[w * 32 + ln] = m; mLs[64 + w * 32 + ln] = ls; }
  }
  __syncthreads();
  if (wid < 2){
    const float m1  = mLs[wid * 32 + ln];
    const float ls1 = mLs[64 + wid * 32 + ln];
    const float mstar = fmaxf(m, m1);
    const float f0 = __builtin_amdgcn_exp2f(m  - mstar);
    const float f1 = __builtin_amdgcn_exp2f(m1 - mstar);
    const float inv = 1.0f / (f0 * ls + f1 * ls1);
    const size_t rowbase = ((size_t)b * SS + q0 + ln) * D_MODEL + h * DK;
    #pragma unroll
    for (int g = 0; g < 4; ++g){
      ushort4 o4;
      o4.x = f2bf((f0 * oa0[4*g + 0] + f1 * oL[(wid * 32 + 4*g + 0) * 64 + lane]) * inv);
      o4.y = f2bf((f0 * oa0[4*g + 1] + f1 * oL[(wid * 32 + 4*g + 1) * 64 + lane]) * inv);
      o4.z = f2bf((f0 * oa0[4*g + 2] + f1 * oL[(wid * 32 + 4*g + 2) * 64 + lane]) * inv);
      o4.w = f2bf((f0 * oa0[4*g + 3] + f1 * oL[(wid * 32 + 4*g + 3) * 64 + lane]) * inv);
      *(ushort4*)&Oc[rowbase + 8*g + 4*hi] = o4;
    }
    #pragma unroll
    for (int g = 0; g < 4; ++g){
      ushort4 o4;
      o4.x = f2bf((f0 * oa1[4*g + 0] + f1 * oL[(wid * 32 + 16 + 4*g + 0) * 64 + lane]) * inv);
      o4.y = f2bf((f0 * oa1[4*g + 1] + f1 * oL[(wid * 32 + 16 + 4*g + 1) * 64 + lane]) * inv);
      o4.z = f2bf((f0 * oa1[4*g + 2] + f1 * oL[(wid * 32 + 16 + 4*g + 2) * 64 + lane]) * inv);
      o4.w = f2bf((f0 * oa1[4*g + 3] + f1 * oL[(wid * 32 + 16 + 4*g + 3) * 64 + lane]) * inv);
      *(ushort4*)&Oc[rowbase + 32 + 8*g + 4*hi] = o4;
    }
  }
}

extern "C" void kernel_launch(void* const* d_in, const int* in_sizes, int n_in,
                              void* d_out, int out_size, void* d_ws, size_t ws_size,
                              hipStream_t stream){
  const float* q  = (const float*)d_in[0];
  const float* k  = (const float*)d_in[1];
  const float* v  = (const float*)d_in[2];
  // d_in[3]: causal mask (deterministic tril) — hardcoded in attn kernel
  const float* wq = (const float*)d_in[4];
  const float* wk = (const float*)d_in[5];
  const float* wv = (const float*)d_in[6];
  const float* wo = (const float*)d_in[7];
  float* out = (float*)d_out;

  char* ws = (char*)d_ws;
  const size_t MB = 1024 * 1024;
  unsigned short* qb     = (unsigned short*)(ws + 0 * MB);
  unsigned short* kb     = (unsigned short*)(ws + 8 * MB);
  unsigned short* vb     = (unsigned short*)(ws + 16 * MB);
  unsigned short* WqkvT  = (unsigned short*)(ws + 24 * MB);   // 6 MB
  unsigned short* woT    = (unsigned short*)(ws + 30 * MB);
  unsigned short* Qh     = (unsigned short*)(ws + 32 * MB);
  unsigned short* Kh     = (unsigned short*)(ws + 40 * MB);
  unsigned short* VhT    = (unsigned short*)(ws + 48 * MB);
  unsigned short* attnb  = (unsigned short*)(ws + 56 * MB);

  const int n4 = (M_TOT * D_MODEL) / 4;   // per tensor
  dim3 gc(n4 / 256, 3);
  cvt3_bf16<<<gc, 256, 0, stream>>>(q, k, v, qb, kb, vb);

  dim3 tg(16, 16, 4);
  transpose_cvt4<<<tg, 256, 0, stream>>>(wq, wk, wv, wo, WqkvT, woT);

  dim3 gqkv(M_TOT / 128, 3 * D_MODEL / 128);   // (32, 24) = 768 blocks
  gemm_qkv<<<gqkv, 256, 0, stream>>>(qb, kb, vb, WqkvT, Qh, Kh, VhT);

  dim3 ga(BB * NH, SS / 64);                   // (32 bh, 32 qblk)
  attn_kernel<<<ga, 256, 0, stream>>>(Qh, Kh, VhT, attnb);

  dim3 go(M_TOT / 64, D_MODEL / 128);          // (64, 8) = 512 blocks
  gemm_o64<<<go, 256, 0, stream>>>(attnb, woT, out);
}